// Round 1
// baseline (3576.293 us; speedup 1.0000x reference)
//
#include <hip/hip_runtime.h>
#include <math.h>

#define H 128
#define NLAYER 2
#define EDG 400000
#define NATOM 600000
#define NREL 13

static constexpr int NODE_N[3]   = {20000, 20000, 10000};
static constexpr int TYPE_OFF[3] = {0, 20000, 40000};
static constexpr int SRC_T[NREL] = {0,0,0,0,0,2,1,2,2,1,1,1,1};
static constexpr int DST_T[NREL] = {2,2,1,1,1,1,1,0,0,0,0,0,2};

// scan segments: 0 = atoms (n=20000), 1..13 = edge relation r-1 (n = N_dst(r))
static constexpr int SEG_N[14]  = {20000,10000,10000,20000,20000,20000,20000,20000,20000,20000,20000,20000,20000,10000};
static constexpr int SEG_CO[14] = {0,20000,30000,40000,60000,80000,100000,120000,140000,160000,180000,200000,220000,240000};
static constexpr int SEG_RO[14] = {0,20001,30002,40003,60004,80005,100006,120007,140008,160009,180010,200011,220012,240013};
#define CNT_TOTAL 250000
#define RP_TOTAL  250014

__device__ __forceinline__ float wave_reduce_sum(float v) {
#pragma unroll
  for (int off = 32; off > 0; off >>= 1) v += __shfl_xor(v, off, 64);
  return v;
}

// ---------------- sort machinery ----------------

__global__ __launch_bounds__(256) void hist_edges(const int* __restrict__ ei, int* __restrict__ cnt) {
  int r = blockIdx.y;
  int e = blockIdx.x * 256 + threadIdx.x;
  if (e >= EDG) return;
  int dst = ei[(size_t)(r * 2 + 1) * EDG + e];
  atomicAdd(&cnt[SEG_CO[r + 1] + dst], 1);
}

__global__ __launch_bounds__(256) void hist_atoms(const int* __restrict__ hd, int* __restrict__ cnt) {
  int i = blockIdx.x * 256 + threadIdx.x;
  if (i >= NATOM) return;
  atomicAdd(&cnt[hd[i]], 1);
}

__global__ __launch_bounds__(256) void scan_kernel(const int* __restrict__ cnt,
                                                   int* __restrict__ rp, int* __restrict__ wp) {
  int seg = blockIdx.x;
  int n = SEG_N[seg], co = SEG_CO[seg], ro = SEG_RO[seg];
  __shared__ int sums[256];
  int chunk = (n + 255) >> 8;
  int b = threadIdx.x * chunk;
  int e = min(b + chunk, n);
  int s = 0;
  for (int i = b; i < e; ++i) s += cnt[co + i];
  sums[threadIdx.x] = s;
  __syncthreads();
  for (int off = 1; off < 256; off <<= 1) {
    int v = (threadIdx.x >= (unsigned)off) ? sums[threadIdx.x - off] : 0;
    __syncthreads();
    sums[threadIdx.x] += v;
    __syncthreads();
  }
  int pre = (threadIdx.x == 0) ? 0 : sums[threadIdx.x - 1];
  for (int i = b; i < e; ++i) {
    int c = cnt[co + i];
    rp[ro + i] = pre;
    wp[co + i] = pre;
    pre += c;
  }
  if (threadIdx.x == 255) rp[ro + n] = sums[255];
}

__global__ __launch_bounds__(256) void scat_edges(const int* __restrict__ ei, int* __restrict__ wp,
                                                  int* __restrict__ perm) {
  int r = blockIdx.y;
  int e = blockIdx.x * 256 + threadIdx.x;
  if (e >= EDG) return;
  int src = ei[(size_t)(r * 2) * EDG + e];
  int dst = ei[(size_t)(r * 2 + 1) * EDG + e];
  int pos = atomicAdd(&wp[SEG_CO[r + 1] + dst], 1);
  perm[(size_t)r * EDG + pos] = src;
}

__global__ __launch_bounds__(256) void scat_atoms(const int* __restrict__ hd, int* __restrict__ wp,
                                                  int* __restrict__ perm) {
  int i = blockIdx.x * 256 + threadIdx.x;
  if (i >= NATOM) return;
  int pos = atomicAdd(&wp[hd[i]], 1);
  perm[pos] = i;
}

// ---------------- atom mean aggregation (in x-space; W_mol folded afterwards) ----------------

__global__ __launch_bounds__(256) void mean_atoms(const float* __restrict__ x_atom,
                                                  const int* __restrict__ rp,
                                                  const int* __restrict__ perm,
                                                  float* __restrict__ Mean) {
  int wave = (blockIdx.x * blockDim.x + threadIdx.x) >> 6;
  int lane = threadIdx.x & 63;
  if (wave >= 20000) return;
  int b = rp[wave], e = rp[wave + 1];
  float s0 = 0.f, s1 = 0.f;
  for (int j = b; j < e; ++j) {
    int a = perm[j];
    float2 v = *(const float2*)(x_atom + (size_t)a * H + 2 * lane);
    s0 += v.x; s1 += v.y;
  }
  float inv = 1.0f / fmaxf((float)(e - b), 1.0f);
  float2 o; o.x = s0 * inv; o.y = s1 * inv;
  *(float2*)(Mean + (size_t)wave * H + 2 * lane) = o;
}

// ---------------- fp32 projection: Y = X @ W (+bias) (+Res), K=N=128 ----------------
// Two independent matmuls per launch via blockIdx.y (xl and xr of one relation).

__global__ __launch_bounds__(256) void proj_kernel(
    const float* __restrict__ X0, const float* __restrict__ W0, const float* __restrict__ B0,
    const float* __restrict__ R0, float* __restrict__ Y0, int N0,
    const float* __restrict__ X1, const float* __restrict__ W1, const float* __restrict__ B1,
    const float* __restrict__ R1, float* __restrict__ Y1, int N1) {
  const float* X; const float* W; const float* Bv; const float* Res; float* Y; int N;
  if (blockIdx.y == 0) { X = X0; W = W0; Bv = B0; Res = R0; Y = Y0; N = N0; }
  else                 { X = X1; W = W1; Bv = B1; Res = R1; Y = Y1; N = N1; }
  int r0 = blockIdx.x * 64;
  if (r0 >= N) return;
  __shared__ float Xs[64][132];          // +4 pad keeps broadcast reads conflict-free, 16B-aligned rows
  int tid = threadIdx.x;
#pragma unroll
  for (int i = 0; i < 8; ++i) {
    int f = tid + 256 * i;               // 2048 float4s = 64 rows x 32
    int row = f >> 5, c4 = (f & 31) << 2;
    float4 v = make_float4(0.f, 0.f, 0.f, 0.f);
    if (r0 + row < N) v = *(const float4*)(X + (size_t)(r0 + row) * H + c4);
    *(float4*)&Xs[row][c4] = v;
  }
  __syncthreads();
  int trow = tid >> 5, tcol = tid & 31;
  float acc[8][4] = {};
#pragma unroll 4
  for (int k = 0; k < 128; ++k) {
    float4 w = *(const float4*)(W + k * H + tcol * 4);
#pragma unroll
    for (int i = 0; i < 8; ++i) {
      float xv = Xs[trow * 8 + i][k];
      acc[i][0] = fmaf(xv, w.x, acc[i][0]);
      acc[i][1] = fmaf(xv, w.y, acc[i][1]);
      acc[i][2] = fmaf(xv, w.z, acc[i][2]);
      acc[i][3] = fmaf(xv, w.w, acc[i][3]);
    }
  }
  float4 bb = make_float4(0.f, 0.f, 0.f, 0.f);
  if (Bv) bb = *(const float4*)(Bv + tcol * 4);
#pragma unroll
  for (int i = 0; i < 8; ++i) {
    int row = r0 + trow * 8 + i;
    if (row < N) {
      float4 ov;
      ov.x = acc[i][0] + bb.x; ov.y = acc[i][1] + bb.y;
      ov.z = acc[i][2] + bb.z; ov.w = acc[i][3] + bb.w;
      if (Res) {
        float4 rv = *(const float4*)(Res + (size_t)row * H + tcol * 4);
        ov.x += rv.x; ov.y += rv.y; ov.z += rv.z; ov.w += rv.w;
      }
      *(float4*)(Y + (size_t)row * H + tcol * 4) = ov;
    }
  }
}

// ---------------- GATv2 edge pass: one wave per dst, online softmax ----------------

__global__ __launch_bounds__(256) void gat_edge_kernel(
    const float* __restrict__ XL, const float* __restrict__ XR,
    const int* __restrict__ rp, const int* __restrict__ psrc,
    const float* __restrict__ att, const float* __restrict__ cbv,
    float* __restrict__ agg, int Nd, int first) {
  int d = (blockIdx.x * blockDim.x + threadIdx.x) >> 6;
  int lane = threadIdx.x & 63;
  if (d >= Nd) return;
  float2 a  = *(const float2*)(att + 2 * lane);
  float2 xr = *(const float2*)(XR + (size_t)d * H + 2 * lane);
  int b = rp[d], e = rp[d + 1];
  float m = -INFINITY, s = 0.f, V0 = 0.f, V1 = 0.f;
  for (int j = b; j < e; ++j) {
    int src = psrc[j];
    float2 xl = *(const float2*)(XL + (size_t)src * H + 2 * lane);
    float v0 = xl.x + xr.x, v1 = xl.y + xr.y;
    float l0 = v0 > 0.f ? v0 : 0.2f * v0;
    float l1 = v1 > 0.f ? v1 : 0.2f * v1;
    float t = wave_reduce_sum(a.x * l0 + a.y * l1);
    float nm = fmaxf(m, t);
    float sc = __expf(m - nm);     // exp(-inf)=0 handles first iteration
    float w  = __expf(t - nm);
    s  = s * sc + w;
    V0 = V0 * sc + w * xl.x;
    V1 = V1 * sc + w * xl.y;
    m = nm;
  }
  float r0 = 0.f, r1 = 0.f;
  if (s > 0.f) { r0 = V0 / s; r1 = V1 / s; }
  float2 cbl = *(const float2*)(cbv + 2 * lane);
  float* ap = agg + (size_t)d * H + 2 * lane;
  float2 o;
  if (first) { o.x = r0 + cbl.x; o.y = r1 + cbl.y; }
  else {
    float2 old = *(float2*)ap;
    o.x = old.x + r0 + cbl.x; o.y = old.y + r1 + cbl.y;
  }
  *(float2*)ap = o;
}

// ---------------- LayerNorm + ReLU ----------------

__global__ __launch_bounds__(256) void ln_relu_kernel(const float* __restrict__ agg,
                                                      const float* __restrict__ g,
                                                      const float* __restrict__ b,
                                                      float* __restrict__ xs) {
  int row = (blockIdx.x * blockDim.x + threadIdx.x) >> 6;
  int lane = threadIdx.x & 63;
  if (row >= 50000) return;
  int t = row < 20000 ? 0 : (row < 40000 ? 1 : 2);
  float2 x = *(const float2*)(agg + (size_t)row * H + 2 * lane);
  float mu = wave_reduce_sum(x.x + x.y) * (1.f / 128.f);
  float d0 = x.x - mu, d1 = x.y - mu;
  float var = wave_reduce_sum(d0 * d0 + d1 * d1) * (1.f / 128.f);
  float inv = 1.0f / sqrtf(var + 1e-5f);
  float2 gg = *(const float2*)(g + t * H + 2 * lane);
  float2 bb = *(const float2*)(b + t * H + 2 * lane);
  float2 o;
  o.x = fmaxf(d0 * inv * gg.x + bb.x, 0.f);
  o.y = fmaxf(d1 * inv * gg.y + bb.y, 0.f);
  *(float2*)(xs + (size_t)row * H + 2 * lane) = o;
}

// ---------------- prediction head: [20000,128] @ [128,2] + bp ----------------

__global__ __launch_bounds__(256) void pred_kernel(const float* __restrict__ xs,
                                                   const float* __restrict__ Wp,
                                                   const float* __restrict__ bp,
                                                   float* __restrict__ out) {
  int row = (blockIdx.x * blockDim.x + threadIdx.x) >> 6;
  int lane = threadIdx.x & 63;
  if (row >= 20000) return;
  float2 x = *(const float2*)(xs + (size_t)row * H + 2 * lane);
  float4 w = *(const float4*)(Wp + 4 * lane);   // Wp[2l][0],Wp[2l][1],Wp[2l+1][0],Wp[2l+1][1]
  float pA = x.x * w.x + x.y * w.z;
  float pB = x.x * w.y + x.y * w.w;
  pA = wave_reduce_sum(pA);
  pB = wave_reduce_sum(pB);
  if (lane == 0) {
    out[(size_t)row * 2 + 0] = pA + bp[0];
    out[(size_t)row * 2 + 1] = pB + bp[1];
  }
}

// ---------------- launch ----------------

extern "C" void kernel_launch(void* const* d_in, const int* in_sizes, int n_in,
                              void* d_out, int out_size, void* d_ws, size_t ws_size,
                              hipStream_t stream) {
  (void)in_sizes; (void)n_in; (void)out_size; (void)ws_size;
  const float* x_atom  = (const float*)d_in[0];
  const float* x_chem  = (const float*)d_in[1];
  const float* x_gene  = (const float*)d_in[2];
  const float* x_assay = (const float*)d_in[3];
  const float* W_mol   = (const float*)d_in[4];
  const float* Wl      = (const float*)d_in[5];
  const float* Wr      = (const float*)d_in[6];
  const float* bl      = (const float*)d_in[7];
  const float* br      = (const float*)d_in[8];
  const float* att_a   = (const float*)d_in[9];
  const float* cb      = (const float*)d_in[10];
  const float* ln_g    = (const float*)d_in[11];
  const float* ln_b    = (const float*)d_in[12];
  const float* Wp      = (const float*)d_in[13];
  const float* bp      = (const float*)d_in[14];
  const int*   hyper   = (const int*)d_in[15];
  const int*   ei      = (const int*)d_in[16];
  float* out = (float*)d_out;

  float* ws = (float*)d_ws;
  size_t o = 0;
  float* xs   = ws + o; o += (size_t)50000 * H;   // concatenated [chem|gene|assay]
  float* agg  = ws + o; o += (size_t)50000 * H;
  float* XL   = ws + o; o += (size_t)20000 * H;   // also reused as atom Mean buffer
  float* XR   = ws + o; o += (size_t)20000 * H;
  int* perm_e = (int*)(ws + o); o += (size_t)NREL * EDG;
  int* perm_a = (int*)(ws + o); o += NATOM;
  int* cnt    = (int*)(ws + o); o += CNT_TOTAL;
  int* wrk    = (int*)(ws + o); o += CNT_TOTAL;
  int* rp     = (int*)(ws + o); o += RP_TOTAL;

  dim3 b256(256);

  // build CSR (atoms + 13 edge relations; edge topology is layer-invariant)
  hipMemsetAsync(cnt, 0, CNT_TOTAL * sizeof(int), stream);
  hist_edges<<<dim3((EDG + 255) / 256, NREL), b256, 0, stream>>>(ei, cnt);
  hist_atoms<<<dim3((NATOM + 255) / 256), b256, 0, stream>>>(hyper, cnt);
  scan_kernel<<<14, 256, 0, stream>>>(cnt, rp, wrk);
  scat_edges<<<dim3((EDG + 255) / 256, NREL), b256, 0, stream>>>(ei, wrk, perm_e);
  scat_atoms<<<dim3((NATOM + 255) / 256), b256, 0, stream>>>(hyper, wrk, perm_a);

  // mean_agg = segment_mean(x_atom); xs[chem] = mean_agg @ W_mol + x_chem  (W_mol folded past the mean)
  mean_atoms<<<dim3(20000 / 4), b256, 0, stream>>>(x_atom, rp, perm_a, XL);
  proj_kernel<<<dim3(313, 1), b256, 0, stream>>>(XL, W_mol, nullptr, x_chem, xs, 20000,
                                                 XL, W_mol, nullptr, x_chem, xs, 20000);
  hipMemcpyAsync(xs + (size_t)20000 * H, x_gene,  (size_t)20000 * H * 4, hipMemcpyDeviceToDevice, stream);
  hipMemcpyAsync(xs + (size_t)40000 * H, x_assay, (size_t)10000 * H * 4, hipMemcpyDeviceToDevice, stream);

  for (int l = 0; l < NLAYER; ++l) {
    bool touched[3] = {false, false, false};
    for (int r = 0; r < NREL; ++r) {
      int sT = SRC_T[r], dT = DST_T[r];
      int Ns = NODE_N[sT], Nd = NODE_N[dT];
      int Nmax = Ns > Nd ? Ns : Nd;
      size_t wi = (size_t)l * NREL + r;
      proj_kernel<<<dim3((Nmax + 63) / 64, 2), b256, 0, stream>>>(
          xs + (size_t)TYPE_OFF[sT] * H, Wl + wi * H * H, bl + wi * H, nullptr, XL, Ns,
          xs + (size_t)TYPE_OFF[dT] * H, Wr + wi * H * H, br + wi * H, nullptr, XR, Nd);
      gat_edge_kernel<<<dim3((Nd + 3) / 4), b256, 0, stream>>>(
          XL, XR, rp + SEG_RO[r + 1], perm_e + (size_t)r * EDG,
          att_a + wi * H, cb + wi * H, agg + (size_t)TYPE_OFF[dT] * H, Nd,
          touched[dT] ? 0 : 1);
      touched[dT] = true;
    }
    ln_relu_kernel<<<dim3(50000 / 4), b256, 0, stream>>>(agg, ln_g + l * 3 * H, ln_b + l * 3 * H, xs);
  }
  pred_kernel<<<dim3(20000 / 4), b256, 0, stream>>>(xs, Wp, bp, out);
}

// Round 2
// 3199.464 us; speedup vs baseline: 1.1178x; 1.1178x over previous
//
#include <hip/hip_runtime.h>
#include <math.h>

#define H 128
#define NLAYER 2
#define EDG 400000
#define NATOM 600000
#define NREL 13
#define SEGS 14
#define RDX 256
#define TILE 4096
#define NPAIR 5800000   // 600000 atoms + 13*400000 edges

static constexpr int NODE_N[3]   = {20000, 20000, 10000};
static constexpr int TYPE_OFF[3] = {0, 20000, 40000};
static constexpr int SRC_T[NREL] = {0,0,0,0,0,2,1,2,2,1,1,1,1};
static constexpr int DST_T[NREL] = {2,2,1,1,1,1,1,0,0,0,0,0,2};

// segments: 0 = atoms (key=hyper_dst<20000), 1..13 = edge relation r-1 (key=dst)
static constexpr int SEG_N[SEGS]  = {20000,10000,10000,20000,20000,20000,20000,20000,20000,20000,20000,20000,20000,10000};
static constexpr int SEG_RO[SEGS] = {0,20001,30002,40003,60004,80005,100006,120007,140008,160009,180010,200011,220012,240013};
#define RP_TOTAL 250014

static constexpr int    SLEN[SEGS] = {600000,EDG,EDG,EDG,EDG,EDG,EDG,EDG,EDG,EDG,EDG,EDG,EDG,EDG};
static constexpr size_t SPOFF[SEGS] = {0,600000,1000000,1400000,1800000,2200000,2600000,3000000,3400000,3800000,4200000,4600000,5000000,5400000};
static constexpr int    RNB[SEGS]  = {147,98,98,98,98,98,98,98,98,98,98,98,98,98};   // ceil(len/TILE)
static constexpr int    RBHOFF[SEGS] = {0,37632,62720,87808,112896,137984,163072,188160,213248,238336,263424,288512,313600,338688};
#define BH_TOTAL 363776

__device__ __forceinline__ float wave_reduce_sum(float v) {
#pragma unroll
  for (int off = 32; off > 0; off >>= 1) v += __shfl_xor(v, off, 64);
  return v;
}

// ---------------- radix sort (2 passes of 8-bit LSB, stable, no global atomics) ----------------

__global__ __launch_bounds__(256) void radix_init(const int* __restrict__ hyper,
                                                  const int* __restrict__ ei,
                                                  int2* __restrict__ A) {
  int s = blockIdx.y;
  int i = blockIdx.x * 256 + threadIdx.x;
  if (i >= SLEN[s]) return;
  int2 p;
  if (s == 0) { p.x = hyper[i]; p.y = i; }
  else {
    int r = s - 1;
    p.x = ei[(size_t)(r * 2 + 1) * EDG + i];  // key = dst
    p.y = ei[(size_t)(r * 2) * EDG + i];      // val = src
  }
  A[SPOFF[s] + i] = p;
}

__global__ __launch_bounds__(256) void radix_count(const int2* __restrict__ in,
                                                   int* __restrict__ bh, int shift) {
  int s = blockIdx.y, bx = blockIdx.x;
  int nb = RNB[s];
  if (bx >= nb) return;
  __shared__ int h[RDX];
  int t = threadIdx.x;
  h[t] = 0;
  __syncthreads();
  int len = SLEN[s];
  size_t poff = SPOFF[s];
#pragma unroll
  for (int i = 0; i < 16; ++i) {
    int p = bx * TILE + i * 256 + t;
    if (p < len) atomicAdd(&h[(in[poff + p].x >> shift) & 255], 1);
  }
  __syncthreads();
  bh[RBHOFF[s] + t * nb + bx] = h[t];
}

__global__ __launch_bounds__(256) void radix_scan(int* __restrict__ bh) {
  int s = blockIdx.x;
  int total = RNB[s] * RDX;
  int off = RBHOFF[s];
  __shared__ int sums[256];
  int t = threadIdx.x;
  int chunk = (total + 255) >> 8;
  int b = t * chunk, e = min(b + chunk, total);
  int acc = 0;
  for (int i = b; i < e; ++i) acc += bh[off + i];
  sums[t] = acc;
  __syncthreads();
  for (int o2 = 1; o2 < 256; o2 <<= 1) {
    int v = (t >= o2) ? sums[t - o2] : 0;
    __syncthreads();
    sums[t] += v;
    __syncthreads();
  }
  int pre = t ? sums[t - 1] : 0;
  for (int i = b; i < e; ++i) { int c = bh[off + i]; bh[off + i] = pre; pre += c; }
}

__global__ __launch_bounds__(256) void radix_scatter(const int2* __restrict__ in,
                                                     int2* __restrict__ out,
                                                     const int* __restrict__ bh, int shift) {
  int s = blockIdx.y, bx = blockIdx.x;
  int nb = RNB[s];
  if (bx >= nb) return;
  __shared__ int2 stg[TILE];       // 32 KB
  __shared__ int wc[4][RDX];
  __shared__ int pw[4][RDX];
  __shared__ int basev[RDX];
  __shared__ int lstart[RDX];
  __shared__ int delta[RDX];
  int t = threadIdx.x;
  int lane = t & 63, w = t >> 6;
  unsigned long long lmask = (1ull << lane) - 1ull;
  int len = SLEN[s];
  size_t poff = SPOFF[s];
  int2 kv[16]; int dg[16]; int rk[16];
  basev[t] = 0;
#pragma unroll
  for (int i = 0; i < 16; ++i) {
    int p = bx * TILE + i * 256 + t;
    kv[i] = (p < len) ? in[poff + p] : make_int2(0, 0);
  }
  __syncthreads();
  // 16 rounds of stable block-wide multi-split ranking (order: i-major, thread-minor)
  for (int i = 0; i < 16; ++i) {
    int p = bx * TILE + i * 256 + t;
    bool valid = p < len;
    int d = (kv[i].x >> shift) & 255;
    wc[0][t] = 0; wc[1][t] = 0; wc[2][t] = 0; wc[3][t] = 0;
    __syncthreads();
    unsigned long long m = __ballot(valid);
#pragma unroll
    for (int b2 = 0; b2 < 8; ++b2) {
      unsigned long long bal = __ballot((d >> b2) & 1);
      m &= ((d >> b2) & 1) ? bal : ~bal;
    }
    int riw = __popcll(m & lmask);
    if (valid && riw == 0) wc[w][d] = __popcll(m);   // one leader per digit per wave
    __syncthreads();
    int s0 = 0;
#pragma unroll
    for (int ww = 0; ww < 4; ++ww) { pw[ww][t] = s0; s0 += wc[ww][t]; }
    __syncthreads();
    dg[i] = d;
    rk[i] = basev[d] + pw[w][d] + riw;
    __syncthreads();
    basev[t] += s0;
    __syncthreads();
  }
  // exclusive scan of per-digit totals -> local start; fetch global base
  int tot = basev[t];
  pw[0][t] = tot;
  __syncthreads();
  for (int o2 = 1; o2 < 256; o2 <<= 1) {
    int v = (t >= o2) ? pw[0][t - o2] : 0;
    __syncthreads();
    pw[0][t] += v;
    __syncthreads();
  }
  int ls = pw[0][t] - tot;
  lstart[t] = ls;
  delta[t] = bh[RBHOFF[s] + t * nb + bx] - ls;
  __syncthreads();
#pragma unroll
  for (int i = 0; i < 16; ++i) {
    int p = bx * TILE + i * 256 + t;
    if (p < len) stg[lstart[dg[i]] + rk[i]] = kv[i];
  }
  __syncthreads();
  int vc = min(len - bx * TILE, TILE);
#pragma unroll
  for (int i = 0; i < 16; ++i) {
    int p = i * 256 + t;
    if (p < vc) {
      int2 pr = stg[p];
      int d = (pr.x >> shift) & 255;
      out[poff + delta[d] + p] = pr;   // coalesced per-digit runs
    }
  }
}

__global__ __launch_bounds__(256) void build_rp(const int2* __restrict__ A, int* __restrict__ rp) {
  int s = blockIdx.y;
  int len = SLEN[s];
  int j = blockIdx.x * 256 + threadIdx.x;
  if (j >= len) return;
  size_t poff = SPOFF[s];
  int ro = SEG_RO[s];
  int k = A[poff + j].x;
  int kprev = (j == 0) ? -1 : A[poff + j - 1].x;
  for (int d = kprev + 1; d <= k; ++d) rp[ro + d] = j;
  if (j == len - 1) {
    int n = SEG_N[s];
    for (int d = k + 1; d <= n; ++d) rp[ro + d] = len;
  }
}

// ---------------- atom mean aggregation (in x-space; W_mol folded afterwards) ----------------

__global__ __launch_bounds__(256) void mean_atoms(const float* __restrict__ x_atom,
                                                  const int* __restrict__ rp,
                                                  const int2* __restrict__ pairs,
                                                  float* __restrict__ Mean) {
  int wave = (blockIdx.x * blockDim.x + threadIdx.x) >> 6;
  int lane = threadIdx.x & 63;
  if (wave >= 20000) return;
  int b = rp[wave], e = rp[wave + 1];
  float s0 = 0.f, s1 = 0.f;
  for (int j = b; j < e; ++j) {
    int a = pairs[j].y;
    float2 v = *(const float2*)(x_atom + (size_t)a * H + 2 * lane);
    s0 += v.x; s1 += v.y;
  }
  float inv = 1.0f / fmaxf((float)(e - b), 1.0f);
  float2 o; o.x = s0 * inv; o.y = s1 * inv;
  *(float2*)(Mean + (size_t)wave * H + 2 * lane) = o;
}

// ---------------- fp32 projection: Y = X @ W (+bias) (+Res), K=N=128 ----------------

__global__ __launch_bounds__(256) void proj_kernel(
    const float* __restrict__ X0, const float* __restrict__ W0, const float* __restrict__ B0,
    const float* __restrict__ R0, float* __restrict__ Y0, int N0,
    const float* __restrict__ X1, const float* __restrict__ W1, const float* __restrict__ B1,
    const float* __restrict__ R1, float* __restrict__ Y1, int N1) {
  const float* X; const float* W; const float* Bv; const float* Res; float* Y; int N;
  if (blockIdx.y == 0) { X = X0; W = W0; Bv = B0; Res = R0; Y = Y0; N = N0; }
  else                 { X = X1; W = W1; Bv = B1; Res = R1; Y = Y1; N = N1; }
  int r0 = blockIdx.x * 64;
  if (r0 >= N) return;
  __shared__ float Xs[64][132];
  int tid = threadIdx.x;
#pragma unroll
  for (int i = 0; i < 8; ++i) {
    int f = tid + 256 * i;
    int row = f >> 5, c4 = (f & 31) << 2;
    float4 v = make_float4(0.f, 0.f, 0.f, 0.f);
    if (r0 + row < N) v = *(const float4*)(X + (size_t)(r0 + row) * H + c4);
    *(float4*)&Xs[row][c4] = v;
  }
  __syncthreads();
  int trow = tid >> 5, tcol = tid & 31;
  float acc[8][4] = {};
#pragma unroll 4
  for (int k = 0; k < 128; ++k) {
    float4 w = *(const float4*)(W + k * H + tcol * 4);
#pragma unroll
    for (int i = 0; i < 8; ++i) {
      float xv = Xs[trow * 8 + i][k];
      acc[i][0] = fmaf(xv, w.x, acc[i][0]);
      acc[i][1] = fmaf(xv, w.y, acc[i][1]);
      acc[i][2] = fmaf(xv, w.z, acc[i][2]);
      acc[i][3] = fmaf(xv, w.w, acc[i][3]);
    }
  }
  float4 bb = make_float4(0.f, 0.f, 0.f, 0.f);
  if (Bv) bb = *(const float4*)(Bv + tcol * 4);
#pragma unroll
  for (int i = 0; i < 8; ++i) {
    int row = r0 + trow * 8 + i;
    if (row < N) {
      float4 ov;
      ov.x = acc[i][0] + bb.x; ov.y = acc[i][1] + bb.y;
      ov.z = acc[i][2] + bb.z; ov.w = acc[i][3] + bb.w;
      if (Res) {
        float4 rv = *(const float4*)(Res + (size_t)row * H + tcol * 4);
        ov.x += rv.x; ov.y += rv.y; ov.z += rv.z; ov.w += rv.w;
      }
      *(float4*)(Y + (size_t)row * H + tcol * 4) = ov;
    }
  }
}

// ---------------- GATv2 edge pass: one wave per dst, online softmax ----------------

__global__ __launch_bounds__(256) void gat_edge_kernel(
    const float* __restrict__ XL, const float* __restrict__ XR,
    const int* __restrict__ rp, const int2* __restrict__ pe,
    const float* __restrict__ att, const float* __restrict__ cbv,
    float* __restrict__ agg, int Nd, int first) {
  int d = (blockIdx.x * blockDim.x + threadIdx.x) >> 6;
  int lane = threadIdx.x & 63;
  if (d >= Nd) return;
  float2 a  = *(const float2*)(att + 2 * lane);
  float2 xr = *(const float2*)(XR + (size_t)d * H + 2 * lane);
  int b = rp[d], e = rp[d + 1];
  float m = -INFINITY, s = 0.f, V0 = 0.f, V1 = 0.f;
  for (int j = b; j < e; ++j) {
    int src = pe[j].y;
    float2 xl = *(const float2*)(XL + (size_t)src * H + 2 * lane);
    float v0 = xl.x + xr.x, v1 = xl.y + xr.y;
    float l0 = v0 > 0.f ? v0 : 0.2f * v0;
    float l1 = v1 > 0.f ? v1 : 0.2f * v1;
    float t = wave_reduce_sum(a.x * l0 + a.y * l1);
    float nm = fmaxf(m, t);
    float sc = __expf(m - nm);
    float w  = __expf(t - nm);
    s  = s * sc + w;
    V0 = V0 * sc + w * xl.x;
    V1 = V1 * sc + w * xl.y;
    m = nm;
  }
  float r0 = 0.f, r1 = 0.f;
  if (s > 0.f) { r0 = V0 / s; r1 = V1 / s; }
  float2 cbl = *(const float2*)(cbv + 2 * lane);
  float* ap = agg + (size_t)d * H + 2 * lane;
  float2 o;
  if (first) { o.x = r0 + cbl.x; o.y = r1 + cbl.y; }
  else {
    float2 old = *(float2*)ap;
    o.x = old.x + r0 + cbl.x; o.y = old.y + r1 + cbl.y;
  }
  *(float2*)ap = o;
}

// ---------------- LayerNorm + ReLU ----------------

__global__ __launch_bounds__(256) void ln_relu_kernel(const float* __restrict__ agg,
                                                      const float* __restrict__ g,
                                                      const float* __restrict__ b,
                                                      float* __restrict__ xs) {
  int row = (blockIdx.x * blockDim.x + threadIdx.x) >> 6;
  int lane = threadIdx.x & 63;
  if (row >= 50000) return;
  int t = row < 20000 ? 0 : (row < 40000 ? 1 : 2);
  float2 x = *(const float2*)(agg + (size_t)row * H + 2 * lane);
  float mu = wave_reduce_sum(x.x + x.y) * (1.f / 128.f);
  float d0 = x.x - mu, d1 = x.y - mu;
  float var = wave_reduce_sum(d0 * d0 + d1 * d1) * (1.f / 128.f);
  float inv = 1.0f / sqrtf(var + 1e-5f);
  float2 gg = *(const float2*)(g + t * H + 2 * lane);
  float2 bb = *(const float2*)(b + t * H + 2 * lane);
  float2 o;
  o.x = fmaxf(d0 * inv * gg.x + bb.x, 0.f);
  o.y = fmaxf(d1 * inv * gg.y + bb.y, 0.f);
  *(float2*)(xs + (size_t)row * H + 2 * lane) = o;
}

// ---------------- prediction head ----------------

__global__ __launch_bounds__(256) void pred_kernel(const float* __restrict__ xs,
                                                   const float* __restrict__ Wp,
                                                   const float* __restrict__ bp,
                                                   float* __restrict__ out) {
  int row = (blockIdx.x * blockDim.x + threadIdx.x) >> 6;
  int lane = threadIdx.x & 63;
  if (row >= 20000) return;
  float2 x = *(const float2*)(xs + (size_t)row * H + 2 * lane);
  float4 w = *(const float4*)(Wp + 4 * lane);
  float pA = x.x * w.x + x.y * w.z;
  float pB = x.x * w.y + x.y * w.w;
  pA = wave_reduce_sum(pA);
  pB = wave_reduce_sum(pB);
  if (lane == 0) {
    out[(size_t)row * 2 + 0] = pA + bp[0];
    out[(size_t)row * 2 + 1] = pB + bp[1];
  }
}

// ---------------- launch ----------------

extern "C" void kernel_launch(void* const* d_in, const int* in_sizes, int n_in,
                              void* d_out, int out_size, void* d_ws, size_t ws_size,
                              hipStream_t stream) {
  (void)in_sizes; (void)n_in; (void)out_size; (void)ws_size;
  const float* x_atom  = (const float*)d_in[0];
  const float* x_chem  = (const float*)d_in[1];
  const float* x_gene  = (const float*)d_in[2];
  const float* x_assay = (const float*)d_in[3];
  const float* W_mol   = (const float*)d_in[4];
  const float* Wl      = (const float*)d_in[5];
  const float* Wr      = (const float*)d_in[6];
  const float* bl      = (const float*)d_in[7];
  const float* br      = (const float*)d_in[8];
  const float* att_a   = (const float*)d_in[9];
  const float* cb      = (const float*)d_in[10];
  const float* ln_g    = (const float*)d_in[11];
  const float* ln_b    = (const float*)d_in[12];
  const float* Wp      = (const float*)d_in[13];
  const float* bp      = (const float*)d_in[14];
  const int*   hyper   = (const int*)d_in[15];
  const int*   ei      = (const int*)d_in[16];
  float* out = (float*)d_out;

  float* ws = (float*)d_ws;
  size_t o = 0;
  float* xs  = ws + o; o += (size_t)50000 * H;      // [chem|gene|assay]
  float* agg = ws + o; o += (size_t)50000 * H;
  int2*  A   = (int2*)(ws + o); o += (size_t)2 * NPAIR;   // final sorted (key,val) pairs
  int2*  Bp2 = (int2*)(ws + o); o += (size_t)2 * NPAIR;   // ping-pong; reused as XL/XR after sort
  int*   rp  = (int*)(ws + o); o += RP_TOTAL;
  int*   bh  = (int*)(ws + o); o += BH_TOTAL;
  float* XL = (float*)Bp2;                    // sort done before first use
  float* XR = XL + (size_t)20000 * H;

  dim3 b256(256);

  // ---- CSR build via stable radix sort (no global atomics) ----
  radix_init<<<dim3(2344, SEGS), b256, 0, stream>>>(hyper, ei, A);
  radix_count<<<dim3(147, SEGS), b256, 0, stream>>>(A, bh, 0);
  radix_scan<<<SEGS, b256, 0, stream>>>(bh);
  radix_scatter<<<dim3(147, SEGS), b256, 0, stream>>>(A, Bp2, bh, 0);
  radix_count<<<dim3(147, SEGS), b256, 0, stream>>>(Bp2, bh, 8);
  radix_scan<<<SEGS, b256, 0, stream>>>(bh);
  radix_scatter<<<dim3(147, SEGS), b256, 0, stream>>>(Bp2, A, bh, 8);
  build_rp<<<dim3(2344, SEGS), b256, 0, stream>>>(A, rp);

  // ---- mean_agg = segment_mean(x_atom); xs[chem] = mean_agg @ W_mol + x_chem ----
  mean_atoms<<<dim3(20000 / 4), b256, 0, stream>>>(x_atom, rp, A, XL);
  proj_kernel<<<dim3(313, 1), b256, 0, stream>>>(XL, W_mol, nullptr, x_chem, xs, 20000,
                                                 XL, W_mol, nullptr, x_chem, xs, 20000);
  hipMemcpyAsync(xs + (size_t)20000 * H, x_gene,  (size_t)20000 * H * 4, hipMemcpyDeviceToDevice, stream);
  hipMemcpyAsync(xs + (size_t)40000 * H, x_assay, (size_t)10000 * H * 4, hipMemcpyDeviceToDevice, stream);

  for (int l = 0; l < NLAYER; ++l) {
    bool touched[3] = {false, false, false};
    for (int r = 0; r < NREL; ++r) {
      int sT = SRC_T[r], dT = DST_T[r];
      int Ns = NODE_N[sT], Nd = NODE_N[dT];
      int Nmax = Ns > Nd ? Ns : Nd;
      size_t wi = (size_t)l * NREL + r;
      proj_kernel<<<dim3((Nmax + 63) / 64, 2), b256, 0, stream>>>(
          xs + (size_t)TYPE_OFF[sT] * H, Wl + wi * H * H, bl + wi * H, nullptr, XL, Ns,
          xs + (size_t)TYPE_OFF[dT] * H, Wr + wi * H * H, br + wi * H, nullptr, XR, Nd);
      gat_edge_kernel<<<dim3((Nd + 3) / 4), b256, 0, stream>>>(
          XL, XR, rp + SEG_RO[r + 1], A + SPOFF[r + 1],
          att_a + wi * H, cb + wi * H, agg + (size_t)TYPE_OFF[dT] * H, Nd,
          touched[dT] ? 0 : 1);
      touched[dT] = true;
    }
    ln_relu_kernel<<<dim3(50000 / 4), b256, 0, stream>>>(agg, ln_g + l * 3 * H, ln_b + l * 3 * H, xs);
  }
  pred_kernel<<<dim3(20000 / 4), b256, 0, stream>>>(xs, Wp, bp, out);
}

// Round 3
// 2367.814 us; speedup vs baseline: 1.5104x; 1.3512x over previous
//
#include <hip/hip_runtime.h>
#include <math.h>

#define H 128
#define NLAYER 2
#define EDG 400000
#define NATOM 600000
#define NREL 13
#define SEGS 14
#define RDX 256
#define TILE 4096
#define NPAIR 5800000   // 600000 atoms + 13*400000 edges

typedef unsigned short u16;
typedef unsigned int u32;
using short8  = __attribute__((ext_vector_type(8))) short;
using ushort8 = __attribute__((ext_vector_type(8))) unsigned short;
using floatx4 = __attribute__((ext_vector_type(4))) float;

static constexpr int NODE_N[3]   = {20000, 20000, 10000};
static constexpr int TYPE_OFF[3] = {0, 20000, 40000};
static constexpr int SRC_T[NREL] = {0,0,0,0,0,2,1,2,2,1,1,1,1};
static constexpr int DST_T[NREL] = {2,2,1,1,1,1,1,0,0,0,0,0,2};

// relations grouped by dst type (for fused GAT)
static constexpr int NREL_OF[3]    = {5, 5, 3};
static constexpr int RELS_OF[3][5] = {{7,8,9,10,11},{2,3,4,5,6},{0,1,12}};

// per-relation offsets (rows) into the XLb / XRb projection tables
static constexpr int XOFF_S[NREL] = {0,20000,40000,60000,80000,100000,110000,130000,140000,150000,170000,190000,210000}; // total 230000
static constexpr int XOFF_D[NREL] = {0,10000,20000,40000,60000,80000,100000,120000,140000,160000,180000,200000,220000}; // total 230000
#define XTOT 230000

// segments: 0 = atoms (key=hyper_dst<20000), 1..13 = edge relation r-1 (key=dst)
static constexpr int SEG_N[SEGS]  = {20000,10000,10000,20000,20000,20000,20000,20000,20000,20000,20000,20000,20000,10000};
static constexpr int SEG_RO[SEGS] = {0,20001,30002,40003,60004,80005,100006,120007,140008,160009,180010,200011,220012,240013};
#define RP_TOTAL 250016

static constexpr int    SLEN[SEGS] = {600000,EDG,EDG,EDG,EDG,EDG,EDG,EDG,EDG,EDG,EDG,EDG,EDG,EDG};
static constexpr size_t SPOFF[SEGS] = {0,600000,1000000,1400000,1800000,2200000,2600000,3000000,3400000,3800000,4200000,4600000,5000000,5400000};
static constexpr int    RNB[SEGS]  = {147,98,98,98,98,98,98,98,98,98,98,98,98,98};   // ceil(len/TILE)
static constexpr int    RBHOFF[SEGS] = {0,37632,62720,87808,112896,137984,163072,188160,213248,238336,263424,288512,313600,338688};
#define BH_TOTAL 363776

__device__ __forceinline__ float wave_reduce_sum(float v) {
#pragma unroll
  for (int off = 32; off > 0; off >>= 1) v += __shfl_xor(v, off, 64);
  return v;
}

__device__ __forceinline__ u16 f2bf(float f) {
  union { float f; u32 u; } c; c.f = f;
  u32 u = c.u + 0x7fffu + ((c.u >> 16) & 1u);   // RNE
  return (u16)(u >> 16);
}
__device__ __forceinline__ float bflo(u32 u) { union { u32 i; float f; } c; c.i = u << 16; return c.f; }
__device__ __forceinline__ float bfhi(u32 u) { union { u32 i; float f; } c; c.i = u & 0xffff0000u; return c.f; }

// ---------------- radix sort (2 passes of 8-bit LSB, stable, no global atomics) ----------------

__global__ __launch_bounds__(256) void radix_init(const int* __restrict__ hyper,
                                                  const int* __restrict__ ei,
                                                  int2* __restrict__ A) {
  int s = blockIdx.y;
  int i = blockIdx.x * 256 + threadIdx.x;
  if (i >= SLEN[s]) return;
  int2 p;
  if (s == 0) { p.x = hyper[i]; p.y = i; }
  else {
    int r = s - 1;
    p.x = ei[(size_t)(r * 2 + 1) * EDG + i];  // key = dst
    p.y = ei[(size_t)(r * 2) * EDG + i];      // val = src
  }
  A[SPOFF[s] + i] = p;
}

__global__ __launch_bounds__(256) void radix_count(const int2* __restrict__ in,
                                                   int* __restrict__ bh, int shift) {
  int s = blockIdx.y, bx = blockIdx.x;
  int nb = RNB[s];
  if (bx >= nb) return;
  __shared__ int h[RDX];
  int t = threadIdx.x;
  h[t] = 0;
  __syncthreads();
  int len = SLEN[s];
  size_t poff = SPOFF[s];
#pragma unroll
  for (int i = 0; i < 16; ++i) {
    int p = bx * TILE + i * 256 + t;
    if (p < len) atomicAdd(&h[(in[poff + p].x >> shift) & 255], 1);
  }
  __syncthreads();
  bh[RBHOFF[s] + t * nb + bx] = h[t];
}

__global__ __launch_bounds__(256) void radix_scan(int* __restrict__ bh) {
  int s = blockIdx.x;
  int total = RNB[s] * RDX;
  int off = RBHOFF[s];
  __shared__ int sums[256];
  int t = threadIdx.x;
  int chunk = (total + 255) >> 8;
  int b = t * chunk, e = min(b + chunk, total);
  int acc = 0;
  for (int i = b; i < e; ++i) acc += bh[off + i];
  sums[t] = acc;
  __syncthreads();
  for (int o2 = 1; o2 < 256; o2 <<= 1) {
    int v = (t >= o2) ? sums[t - o2] : 0;
    __syncthreads();
    sums[t] += v;
    __syncthreads();
  }
  int pre = t ? sums[t - 1] : 0;
  for (int i = b; i < e; ++i) { int c = bh[off + i]; bh[off + i] = pre; pre += c; }
}

__global__ __launch_bounds__(256) void radix_scatter(const int2* __restrict__ in,
                                                     int2* __restrict__ out,
                                                     const int* __restrict__ bh, int shift) {
  int s = blockIdx.y, bx = blockIdx.x;
  int nb = RNB[s];
  if (bx >= nb) return;
  __shared__ int2 stg[TILE];
  __shared__ int wc[4][RDX];
  __shared__ int pw[4][RDX];
  __shared__ int basev[RDX];
  __shared__ int lstart[RDX];
  __shared__ int delta[RDX];
  int t = threadIdx.x;
  int lane = t & 63, w = t >> 6;
  unsigned long long lmask = (1ull << lane) - 1ull;
  int len = SLEN[s];
  size_t poff = SPOFF[s];
  int2 kv[16]; int dg[16]; int rk[16];
  basev[t] = 0;
#pragma unroll
  for (int i = 0; i < 16; ++i) {
    int p = bx * TILE + i * 256 + t;
    kv[i] = (p < len) ? in[poff + p] : make_int2(0, 0);
  }
  __syncthreads();
  for (int i = 0; i < 16; ++i) {
    int p = bx * TILE + i * 256 + t;
    bool valid = p < len;
    int d = (kv[i].x >> shift) & 255;
    wc[0][t] = 0; wc[1][t] = 0; wc[2][t] = 0; wc[3][t] = 0;
    __syncthreads();
    unsigned long long m = __ballot(valid);
#pragma unroll
    for (int b2 = 0; b2 < 8; ++b2) {
      unsigned long long bal = __ballot((d >> b2) & 1);
      m &= ((d >> b2) & 1) ? bal : ~bal;
    }
    int riw = __popcll(m & lmask);
    if (valid && riw == 0) wc[w][d] = __popcll(m);
    __syncthreads();
    int s0 = 0;
#pragma unroll
    for (int ww = 0; ww < 4; ++ww) { pw[ww][t] = s0; s0 += wc[ww][t]; }
    __syncthreads();
    dg[i] = d;
    rk[i] = basev[d] + pw[w][d] + riw;
    __syncthreads();
    basev[t] += s0;
    __syncthreads();
  }
  int tot = basev[t];
  pw[0][t] = tot;
  __syncthreads();
  for (int o2 = 1; o2 < 256; o2 <<= 1) {
    int v = (t >= o2) ? pw[0][t - o2] : 0;
    __syncthreads();
    pw[0][t] += v;
    __syncthreads();
  }
  int ls = pw[0][t] - tot;
  lstart[t] = ls;
  delta[t] = bh[RBHOFF[s] + t * nb + bx] - ls;
  __syncthreads();
#pragma unroll
  for (int i = 0; i < 16; ++i) {
    int p = bx * TILE + i * 256 + t;
    if (p < len) stg[lstart[dg[i]] + rk[i]] = kv[i];
  }
  __syncthreads();
  int vc = min(len - bx * TILE, TILE);
#pragma unroll
  for (int i = 0; i < 16; ++i) {
    int p = i * 256 + t;
    if (p < vc) {
      int2 pr = stg[p];
      int d = (pr.x >> shift) & 255;
      out[poff + delta[d] + p] = pr;
    }
  }
}

__global__ __launch_bounds__(256) void build_rp(const int2* __restrict__ A, int* __restrict__ rp) {
  int s = blockIdx.y;
  int len = SLEN[s];
  int j = blockIdx.x * 256 + threadIdx.x;
  if (j >= len) return;
  size_t poff = SPOFF[s];
  int ro = SEG_RO[s];
  int k = A[poff + j].x;
  int kprev = (j == 0) ? -1 : A[poff + j - 1].x;
  for (int d = kprev + 1; d <= k; ++d) rp[ro + d] = j;
  if (j == len - 1) {
    int n = SEG_N[s];
    for (int d = k + 1; d <= n; ++d) rp[ro + d] = len;
  }
}

// ---------------- atom mean aggregation (in x-space; W_mol folded afterwards) ----------------

__global__ __launch_bounds__(256) void mean_atoms(const float* __restrict__ x_atom,
                                                  const int* __restrict__ rp,
                                                  const int2* __restrict__ pairs,
                                                  float* __restrict__ Mean) {
  int wave = (blockIdx.x * blockDim.x + threadIdx.x) >> 6;
  int lane = threadIdx.x & 63;
  if (wave >= 20000) return;
  int b = rp[wave], e = rp[wave + 1];
  float s0 = 0.f, s1 = 0.f;
  for (int j = b; j < e; ++j) {
    int a = pairs[j].y;
    float2 v = *(const float2*)(x_atom + (size_t)a * H + 2 * lane);
    s0 += v.x; s1 += v.y;
  }
  float inv = 1.0f / fmaxf((float)(e - b), 1.0f);
  float2 o; o.x = s0 * inv; o.y = s1 * inv;
  *(float2*)(Mean + (size_t)wave * H + 2 * lane) = o;
}

// ---------------- fp32 projection (used once, for W_mol): Y = X @ W + Res ----------------

__global__ __launch_bounds__(256) void proj_kernel(
    const float* __restrict__ X, const float* __restrict__ W,
    const float* __restrict__ Res, float* __restrict__ Y, int N) {
  int r0 = blockIdx.x * 64;
  if (r0 >= N) return;
  __shared__ float Xs[64][132];
  int tid = threadIdx.x;
#pragma unroll
  for (int i = 0; i < 8; ++i) {
    int f = tid + 256 * i;
    int row = f >> 5, c4 = (f & 31) << 2;
    float4 v = make_float4(0.f, 0.f, 0.f, 0.f);
    if (r0 + row < N) v = *(const float4*)(X + (size_t)(r0 + row) * H + c4);
    *(float4*)&Xs[row][c4] = v;
  }
  __syncthreads();
  int trow = tid >> 5, tcol = tid & 31;
  float acc[8][4] = {};
#pragma unroll 4
  for (int k = 0; k < 128; ++k) {
    float4 w = *(const float4*)(W + k * H + tcol * 4);
#pragma unroll
    for (int i = 0; i < 8; ++i) {
      float xv = Xs[trow * 8 + i][k];
      acc[i][0] = fmaf(xv, w.x, acc[i][0]);
      acc[i][1] = fmaf(xv, w.y, acc[i][1]);
      acc[i][2] = fmaf(xv, w.z, acc[i][2]);
      acc[i][3] = fmaf(xv, w.w, acc[i][3]);
    }
  }
#pragma unroll
  for (int i = 0; i < 8; ++i) {
    int row = r0 + trow * 8 + i;
    if (row < N) {
      float4 rv = *(const float4*)(Res + (size_t)row * H + tcol * 4);
      float4 ov;
      ov.x = acc[i][0] + rv.x; ov.y = acc[i][1] + rv.y;
      ov.z = acc[i][2] + rv.z; ov.w = acc[i][3] + rv.w;
      *(float4*)(Y + (size_t)row * H + tcol * 4) = ov;
    }
  }
}

// ---------------- converts ----------------

// xsb = bf16([xs_chem(computed) | x_gene | x_assay])
__global__ __launch_bounds__(256) void conv_xs(const float* __restrict__ xs,
                                               const float* __restrict__ x_gene,
                                               const float* __restrict__ x_assay,
                                               u16* __restrict__ xsb) {
  int idx = (blockIdx.x * 256 + threadIdx.x) * 4;
  if (idx >= 50000 * H) return;
  int row = idx >> 7;
  const float* src;
  if (row < 20000)      src = xs + idx;
  else if (row < 40000) src = x_gene + (idx - 20000 * H);
  else                  src = x_assay + (idx - 40000 * H);
  float4 v = *(const float4*)src;
  u32 p0 = (u32)f2bf(v.x) | ((u32)f2bf(v.y) << 16);
  u32 p1 = (u32)f2bf(v.z) | ((u32)f2bf(v.w) << 16);
  u32* o = (u32*)(xsb + idx);
  o[0] = p0; o[1] = p1;
}

// WB[(mat*2+side)][n][k] = bf16( (side?Wr:Wl)[mat][k][n] )   (transposed for MFMA B-frags)
__global__ __launch_bounds__(256) void conv_weights(const float* __restrict__ Wl,
                                                    const float* __restrict__ Wr,
                                                    u16* __restrict__ WB) {
  int mat = blockIdx.x;      // 0..25  (l*NREL+r)
  int side = blockIdx.y;     // 0..1
  const float* W = (side ? Wr : Wl) + (size_t)mat * H * H;
  u16* O = WB + ((size_t)mat * 2 + side) * H * H;
  for (int f = threadIdx.x; f < H * H; f += 256) {
    int n = f >> 7, k = f & 127;
    O[f] = f2bf(W[k * H + n]);
  }
}

// ---------------- batched bf16 MFMA projection: all 26 GEMMs of one layer ----------------
// Y[side r] = bf16( xsb[type] @ W[l,r,side] + bias )

__global__ __launch_bounds__(256) void proj_mfma(
    const u16* __restrict__ xsb, const u16* __restrict__ WB,
    const float* __restrict__ bl, const float* __restrict__ br,
    u16* __restrict__ XLb, u16* __restrict__ XRb, int layer) {
  int by = blockIdx.y;               // 0..25
  int r = by >> 1, side = by & 1;
  int typ = side ? DST_T[r] : SRC_T[r];
  int N = NODE_N[typ];
  int r0 = blockIdx.x * 64;
  if (r0 >= N) return;
  const u16* X = xsb + (size_t)TYPE_OFF[typ] * H;
  const u16* W = WB + ((size_t)(layer * NREL + r) * 2 + side) * H * H;
  const float* bias = (side ? br : bl) + (size_t)(layer * NREL + r) * H;
  u16* Y = side ? (XRb + (size_t)XOFF_D[r] * H) : (XLb + (size_t)XOFF_S[r] * H);

  __shared__ u16 Xs[64 * 136];       // X tile, stride 136; reused as C tile in epilogue
  __shared__ u16 Ws[128 * 136];      // W^T tile [n][k], stride 136
  int tid = threadIdx.x;
#pragma unroll
  for (int i = 0; i < 4; ++i) {
    int f = tid + 256 * i;           // 1024 chunks: 64 rows x 16 segs of 8 bf16
    int row = f >> 4, seg = f & 15;
    ushort8 v = {};
    if (r0 + row < N) v = *(const ushort8*)(X + (size_t)(r0 + row) * H + seg * 8);
    *(ushort8*)(Xs + row * 136 + seg * 8) = v;
  }
#pragma unroll
  for (int i = 0; i < 8; ++i) {
    int f = tid + 256 * i;           // 2048 chunks: 128 rows x 16 segs
    int row = f >> 4, seg = f & 15;
    *(ushort8*)(Ws + row * 136 + seg * 8) = *(const ushort8*)(W + row * H + seg * 8);
  }
  __syncthreads();

  int w = tid >> 6, lane = tid & 63;
  int g = lane >> 4, l16 = lane & 15;
  floatx4 acc[4][2] = {};
#pragma unroll
  for (int kt = 0; kt < 4; ++kt) {
    int k0 = kt * 32 + g * 8;
    short8 a[4], b[2];
#pragma unroll
    for (int rt = 0; rt < 4; ++rt) a[rt] = *(const short8*)(Xs + (rt * 16 + l16) * 136 + k0);
#pragma unroll
    for (int ct = 0; ct < 2; ++ct) b[ct] = *(const short8*)(Ws + (w * 32 + ct * 16 + l16) * 136 + k0);
#pragma unroll
    for (int rt = 0; rt < 4; ++rt)
#pragma unroll
      for (int ct = 0; ct < 2; ++ct)
        acc[rt][ct] = __builtin_amdgcn_mfma_f32_16x16x32_bf16(a[rt], b[ct], acc[rt][ct], 0, 0, 0);
  }
  __syncthreads();                   // done reading Xs; reuse as C tile
  float bv0 = bias[w * 32 + l16];
  float bv1 = bias[w * 32 + 16 + l16];
#pragma unroll
  for (int rt = 0; rt < 4; ++rt)
#pragma unroll
    for (int ct = 0; ct < 2; ++ct) {
      float bv = ct ? bv1 : bv0;
      int col = w * 32 + ct * 16 + l16;
#pragma unroll
      for (int reg = 0; reg < 4; ++reg) {
        int row = rt * 16 + g * 4 + reg;
        Xs[row * 136 + col] = f2bf(acc[rt][ct][reg] + bv);
      }
    }
  __syncthreads();
#pragma unroll
  for (int i = 0; i < 4; ++i) {
    int f = tid + 256 * i;
    int row = f >> 4, seg = f & 15;
    if (r0 + row < N)
      *(ushort8*)(Y + (size_t)(r0 + row) * H + seg * 8) = *(const ushort8*)(Xs + row * 136 + seg * 8);
  }
}

// ---------------- fused GATv2 edge pass: all relations of one dst type ----------------

__global__ __launch_bounds__(256) void gat_fused(
    const u16* __restrict__ XLb, const u16* __restrict__ XRb,
    const int* __restrict__ rp, const int2* __restrict__ A,
    const float* __restrict__ att_a, const float* __restrict__ cbv,
    float* __restrict__ agg, int layer, int dt) {
  int d = (blockIdx.x * blockDim.x + threadIdx.x) >> 6;
  int lane = threadIdx.x & 63;
  if (d >= NODE_N[dt]) return;
  float o0 = 0.f, o1 = 0.f;
  int nr = NREL_OF[dt];
  for (int rr = 0; rr < nr; ++rr) {
    int r = RELS_OF[dt][rr];
    size_t wi = (size_t)layer * NREL + r;
    const u16* XL = XLb + (size_t)XOFF_S[r] * H;
    const u16* XR = XRb + (size_t)XOFF_D[r] * H;
    u32 ur = *(const u32*)(XR + (size_t)d * H + 2 * lane);
    float xr0 = bflo(ur), xr1 = bfhi(ur);
    float2 a2 = *(const float2*)(att_a + wi * H + 2 * lane);
    const int* rpr = rp + SEG_RO[r + 1];
    const int2* pe = A + SPOFF[r + 1];
    int b = rpr[d], e = rpr[d + 1];
    float m = -INFINITY, s = 0.f, V0 = 0.f, V1 = 0.f;
    for (int j = b; j < e; ++j) {
      int src = pe[j].y;
      u32 ul = *(const u32*)(XL + (size_t)src * H + 2 * lane);
      float xl0 = bflo(ul), xl1 = bfhi(ul);
      float v0 = xl0 + xr0, v1 = xl1 + xr1;
      float l0 = v0 > 0.f ? v0 : 0.2f * v0;
      float l1 = v1 > 0.f ? v1 : 0.2f * v1;
      float t = wave_reduce_sum(a2.x * l0 + a2.y * l1);
      float nm = fmaxf(m, t);
      float sc = __expf(m - nm);
      float wgt = __expf(t - nm);
      s = s * sc + wgt;
      V0 = V0 * sc + wgt * xl0;
      V1 = V1 * sc + wgt * xl1;
      m = nm;
    }
    if (s > 0.f) { o0 += V0 / s; o1 += V1 / s; }
    float2 cb2 = *(const float2*)(cbv + wi * H + 2 * lane);
    o0 += cb2.x; o1 += cb2.y;
  }
  float2 o; o.x = o0; o.y = o1;
  *(float2*)(agg + (size_t)(TYPE_OFF[dt] + d) * H + 2 * lane) = o;
}

// ---------------- LayerNorm + ReLU (fp32 in, bf16 out) ----------------

__global__ __launch_bounds__(256) void ln_relu_kernel(const float* __restrict__ agg,
                                                      const float* __restrict__ g,
                                                      const float* __restrict__ b,
                                                      u16* __restrict__ xsb) {
  int row = (blockIdx.x * blockDim.x + threadIdx.x) >> 6;
  int lane = threadIdx.x & 63;
  if (row >= 50000) return;
  int t = row < 20000 ? 0 : (row < 40000 ? 1 : 2);
  float2 x = *(const float2*)(agg + (size_t)row * H + 2 * lane);
  float mu = wave_reduce_sum(x.x + x.y) * (1.f / 128.f);
  float d0 = x.x - mu, d1 = x.y - mu;
  float var = wave_reduce_sum(d0 * d0 + d1 * d1) * (1.f / 128.f);
  float inv = 1.0f / sqrtf(var + 1e-5f);
  float2 gg = *(const float2*)(g + t * H + 2 * lane);
  float2 bb = *(const float2*)(b + t * H + 2 * lane);
  float o0 = fmaxf(d0 * inv * gg.x + bb.x, 0.f);
  float o1 = fmaxf(d1 * inv * gg.y + bb.y, 0.f);
  u32 pk = (u32)f2bf(o0) | ((u32)f2bf(o1) << 16);
  *(u32*)(xsb + (size_t)row * H + 2 * lane) = pk;
}

// ---------------- prediction head: bf16[20000,128] @ fp32[128,2] + bp ----------------

__global__ __launch_bounds__(256) void pred_kernel(const u16* __restrict__ xsb,
                                                   const float* __restrict__ Wp,
                                                   const float* __restrict__ bp,
                                                   float* __restrict__ out) {
  int row = (blockIdx.x * blockDim.x + threadIdx.x) >> 6;
  int lane = threadIdx.x & 63;
  if (row >= 20000) return;
  u32 u = *(const u32*)(xsb + (size_t)row * H + 2 * lane);
  float x0 = bflo(u), x1 = bfhi(u);
  float4 w = *(const float4*)(Wp + 4 * lane);
  float pA = x0 * w.x + x1 * w.z;
  float pB = x0 * w.y + x1 * w.w;
  pA = wave_reduce_sum(pA);
  pB = wave_reduce_sum(pB);
  if (lane == 0) {
    out[(size_t)row * 2 + 0] = pA + bp[0];
    out[(size_t)row * 2 + 1] = pB + bp[1];
  }
}

// ---------------- launch ----------------

extern "C" void kernel_launch(void* const* d_in, const int* in_sizes, int n_in,
                              void* d_out, int out_size, void* d_ws, size_t ws_size,
                              hipStream_t stream) {
  (void)in_sizes; (void)n_in; (void)out_size; (void)ws_size;
  const float* x_atom  = (const float*)d_in[0];
  const float* x_chem  = (const float*)d_in[1];
  const float* x_gene  = (const float*)d_in[2];
  const float* x_assay = (const float*)d_in[3];
  const float* W_mol   = (const float*)d_in[4];
  const float* Wl      = (const float*)d_in[5];
  const float* Wr      = (const float*)d_in[6];
  const float* bl      = (const float*)d_in[7];
  const float* br      = (const float*)d_in[8];
  const float* att_a   = (const float*)d_in[9];
  const float* cb      = (const float*)d_in[10];
  const float* ln_g    = (const float*)d_in[11];
  const float* ln_b    = (const float*)d_in[12];
  const float* Wp      = (const float*)d_in[13];
  const float* bp      = (const float*)d_in[14];
  const int*   hyper   = (const int*)d_in[15];
  const int*   ei      = (const int*)d_in[16];
  float* out = (float*)d_out;

  float* ws = (float*)d_ws;
  size_t o = 0;
  float* xs   = ws + o; o += (size_t)50000 * H;          // fp32 initial features (chem part computed)
  float* agg  = ws + o; o += (size_t)50000 * H;          // fp32 per-layer aggregate
  float* Mean = ws + o; o += (size_t)20000 * H;          // atom segment means
  int2*  A    = (int2*)(ws + o); o += (size_t)2 * NPAIR; // sorted (key,val)
  int2*  Bp2  = (int2*)(ws + o); o += (size_t)2 * NPAIR; // ping-pong
  int*   rp   = (int*)(ws + o); o += RP_TOTAL;
  int*   bh   = (int*)(ws + o); o += BH_TOTAL;
  u16*   xsb  = (u16*)(ws + o); o += (size_t)50000 * H / 2;   // bf16 features
  u16*   WB   = (u16*)(ws + o); o += (size_t)52 * H * H / 2;  // bf16 transposed weights
  u16*   XLb  = (u16*)(ws + o); o += (size_t)XTOT * H / 2;    // bf16 src-side projections
  u16*   XRb  = (u16*)(ws + o); o += (size_t)XTOT * H / 2;    // bf16 dst-side projections

  dim3 b256(256);

  // ---- CSR build via stable radix sort (no global atomics) ----
  radix_init<<<dim3(2344, SEGS), b256, 0, stream>>>(hyper, ei, A);
  radix_count<<<dim3(147, SEGS), b256, 0, stream>>>(A, bh, 0);
  radix_scan<<<SEGS, b256, 0, stream>>>(bh);
  radix_scatter<<<dim3(147, SEGS), b256, 0, stream>>>(A, Bp2, bh, 0);
  radix_count<<<dim3(147, SEGS), b256, 0, stream>>>(Bp2, bh, 8);
  radix_scan<<<SEGS, b256, 0, stream>>>(bh);
  radix_scatter<<<dim3(147, SEGS), b256, 0, stream>>>(Bp2, A, bh, 8);
  build_rp<<<dim3(2344, SEGS), b256, 0, stream>>>(A, rp);

  // ---- xs[chem] = segment_mean(x_atom) @ W_mol + x_chem; xsb = bf16 features ----
  mean_atoms<<<dim3(20000 / 4), b256, 0, stream>>>(x_atom, rp, A, Mean);
  proj_kernel<<<dim3(313), b256, 0, stream>>>(Mean, W_mol, x_chem, xs, 20000);
  conv_xs<<<dim3(6250), b256, 0, stream>>>(xs, x_gene, x_assay, xsb);
  conv_weights<<<dim3(26, 2), b256, 0, stream>>>(Wl, Wr, WB);

  for (int l = 0; l < NLAYER; ++l) {
    proj_mfma<<<dim3(313, 26), b256, 0, stream>>>(xsb, WB, bl, br, XLb, XRb, l);
    for (int dt = 0; dt < 3; ++dt)
      gat_fused<<<dim3((NODE_N[dt] + 3) / 4), b256, 0, stream>>>(
          XLb, XRb, rp, A, att_a, cb, agg, l, dt);
    ln_relu_kernel<<<dim3(50000 / 4), b256, 0, stream>>>(agg, ln_g + l * 3 * H, ln_b + l * 3 * H, xsb);
  }
  pred_kernel<<<dim3(20000 / 4), b256, 0, stream>>>(xsb, Wp, bp, out);
}

// Round 4
// 1710.300 us; speedup vs baseline: 2.0910x; 1.3844x over previous
//
#include <hip/hip_runtime.h>
#include <math.h>

#define H 128
#define NLAYER 2
#define EDG 400000
#define NATOM 600000
#define NREL 13
#define SEGS 14
#define RDX 256
#define TILE 4096
#define NPAIR 5800000   // 600000 atoms + 13*400000 edges

typedef unsigned short u16;
typedef unsigned int u32;
using short8  = __attribute__((ext_vector_type(8))) short;
using ushort8 = __attribute__((ext_vector_type(8))) unsigned short;
using floatx4 = __attribute__((ext_vector_type(4))) float;

static constexpr int NODE_N[3]   = {20000, 20000, 10000};
static constexpr int TYPE_OFF[3] = {0, 20000, 40000};
static constexpr int SRC_T[NREL] = {0,0,0,0,0,2,1,2,2,1,1,1,1};
static constexpr int DST_T[NREL] = {2,2,1,1,1,1,1,0,0,0,0,0,2};

// relations grouped by dst type (for fused GAT)
static constexpr int NREL_OF[3]    = {5, 5, 3};
static constexpr int RELS_OF[3][5] = {{7,8,9,10,11},{2,3,4,5,6},{0,1,12}};

// per-relation offsets (rows) into the XLb / XRb projection tables
static constexpr int XOFF_S[NREL] = {0,20000,40000,60000,80000,100000,110000,130000,140000,150000,170000,190000,210000}; // total 230000
static constexpr int XOFF_D[NREL] = {0,10000,20000,40000,60000,80000,100000,120000,140000,160000,180000,200000,220000}; // total 230000
#define XTOT 230000

// segments: 0 = atoms (key=hyper_dst<20000), 1..13 = edge relation r-1 (key=dst)
static constexpr int SEG_N[SEGS]  = {20000,10000,10000,20000,20000,20000,20000,20000,20000,20000,20000,20000,20000,10000};
static constexpr int SEG_RO[SEGS] = {0,20001,30002,40003,60004,80005,100006,120007,140008,160009,180010,200011,220012,240013};
#define RP_TOTAL 250016

static constexpr int    SLEN[SEGS] = {600000,EDG,EDG,EDG,EDG,EDG,EDG,EDG,EDG,EDG,EDG,EDG,EDG,EDG};
static constexpr size_t SPOFF[SEGS] = {0,600000,1000000,1400000,1800000,2200000,2600000,3000000,3400000,3800000,4200000,4600000,5000000,5400000};
static constexpr int    RNB[SEGS]  = {147,98,98,98,98,98,98,98,98,98,98,98,98,98};   // ceil(len/TILE)
static constexpr int    RBHOFF[SEGS] = {0,37632,62720,87808,112896,137984,163072,188160,213248,238336,263424,288512,313600,338688};
#define BH_TOTAL 363776

__device__ __forceinline__ float wave_reduce_sum(float v) {
#pragma unroll
  for (int off = 32; off > 0; off >>= 1) v += __shfl_xor(v, off, 64);
  return v;
}

__device__ __forceinline__ u16 f2bf(float f) {
  union { float f; u32 u; } c; c.f = f;
  u32 u = c.u + 0x7fffu + ((c.u >> 16) & 1u);   // RNE
  return (u16)(u >> 16);
}
__device__ __forceinline__ float bf2f(u16 h) { union { u32 i; float f; } c; c.i = (u32)h << 16; return c.f; }
__device__ __forceinline__ float bflo(u32 u) { union { u32 i; float f; } c; c.i = u << 16; return c.f; }
__device__ __forceinline__ float bfhi(u32 u) { union { u32 i; float f; } c; c.i = u & 0xffff0000u; return c.f; }

// ---------------- radix sort (2 passes of 8-bit LSB, stable, no global atomics) ----------------

__global__ __launch_bounds__(256) void radix_init(const int* __restrict__ hyper,
                                                  const int* __restrict__ ei,
                                                  int2* __restrict__ A) {
  int s = blockIdx.y;
  int i = blockIdx.x * 256 + threadIdx.x;
  if (i >= SLEN[s]) return;
  int2 p;
  if (s == 0) { p.x = hyper[i]; p.y = i; }
  else {
    int r = s - 1;
    p.x = ei[(size_t)(r * 2 + 1) * EDG + i];  // key = dst
    p.y = ei[(size_t)(r * 2) * EDG + i];      // val = src
  }
  A[SPOFF[s] + i] = p;
}

__global__ __launch_bounds__(256) void radix_count(const int2* __restrict__ in,
                                                   int* __restrict__ bh, int shift) {
  int s = blockIdx.y, bx = blockIdx.x;
  int nb = RNB[s];
  if (bx >= nb) return;
  __shared__ int h[RDX];
  int t = threadIdx.x;
  h[t] = 0;
  __syncthreads();
  int len = SLEN[s];
  size_t poff = SPOFF[s];
#pragma unroll
  for (int i = 0; i < 16; ++i) {
    int p = bx * TILE + i * 256 + t;
    if (p < len) atomicAdd(&h[(in[poff + p].x >> shift) & 255], 1);
  }
  __syncthreads();
  bh[RBHOFF[s] + t * nb + bx] = h[t];
}

__global__ __launch_bounds__(256) void radix_scan(int* __restrict__ bh) {
  int s = blockIdx.x;
  int total = RNB[s] * RDX;
  int off = RBHOFF[s];
  __shared__ int sums[256];
  int t = threadIdx.x;
  int chunk = (total + 255) >> 8;
  int b = t * chunk, e = min(b + chunk, total);
  int acc = 0;
  for (int i = b; i < e; ++i) acc += bh[off + i];
  sums[t] = acc;
  __syncthreads();
  for (int o2 = 1; o2 < 256; o2 <<= 1) {
    int v = (t >= o2) ? sums[t - o2] : 0;
    __syncthreads();
    sums[t] += v;
    __syncthreads();
  }
  int pre = t ? sums[t - 1] : 0;
  for (int i = b; i < e; ++i) { int c = bh[off + i]; bh[off + i] = pre; pre += c; }
}

__global__ __launch_bounds__(256) void radix_scatter(const int2* __restrict__ in,
                                                     int2* __restrict__ out,
                                                     const int* __restrict__ bh, int shift) {
  int s = blockIdx.y, bx = blockIdx.x;
  int nb = RNB[s];
  if (bx >= nb) return;
  __shared__ int2 stg[TILE];
  __shared__ int wc[4][RDX];
  __shared__ int pw[4][RDX];
  __shared__ int basev[RDX];
  __shared__ int lstart[RDX];
  __shared__ int delta[RDX];
  int t = threadIdx.x;
  int lane = t & 63, w = t >> 6;
  unsigned long long lmask = (1ull << lane) - 1ull;
  int len = SLEN[s];
  size_t poff = SPOFF[s];
  int2 kv[16]; int dg[16]; int rk[16];
  basev[t] = 0;
#pragma unroll
  for (int i = 0; i < 16; ++i) {
    int p = bx * TILE + i * 256 + t;
    kv[i] = (p < len) ? in[poff + p] : make_int2(0, 0);
  }
  __syncthreads();
  for (int i = 0; i < 16; ++i) {
    int p = bx * TILE + i * 256 + t;
    bool valid = p < len;
    int d = (kv[i].x >> shift) & 255;
    wc[0][t] = 0; wc[1][t] = 0; wc[2][t] = 0; wc[3][t] = 0;
    __syncthreads();
    unsigned long long m = __ballot(valid);
#pragma unroll
    for (int b2 = 0; b2 < 8; ++b2) {
      unsigned long long bal = __ballot((d >> b2) & 1);
      m &= ((d >> b2) & 1) ? bal : ~bal;
    }
    int riw = __popcll(m & lmask);
    if (valid && riw == 0) wc[w][d] = __popcll(m);
    __syncthreads();
    int s0 = 0;
#pragma unroll
    for (int ww = 0; ww < 4; ++ww) { pw[ww][t] = s0; s0 += wc[ww][t]; }
    __syncthreads();
    dg[i] = d;
    rk[i] = basev[d] + pw[w][d] + riw;
    __syncthreads();
    basev[t] += s0;
    __syncthreads();
  }
  int tot = basev[t];
  pw[0][t] = tot;
  __syncthreads();
  for (int o2 = 1; o2 < 256; o2 <<= 1) {
    int v = (t >= o2) ? pw[0][t - o2] : 0;
    __syncthreads();
    pw[0][t] += v;
    __syncthreads();
  }
  int ls = pw[0][t] - tot;
  lstart[t] = ls;
  delta[t] = bh[RBHOFF[s] + t * nb + bx] - ls;
  __syncthreads();
#pragma unroll
  for (int i = 0; i < 16; ++i) {
    int p = bx * TILE + i * 256 + t;
    if (p < len) stg[lstart[dg[i]] + rk[i]] = kv[i];
  }
  __syncthreads();
  int vc = min(len - bx * TILE, TILE);
#pragma unroll
  for (int i = 0; i < 16; ++i) {
    int p = i * 256 + t;
    if (p < vc) {
      int2 pr = stg[p];
      int d = (pr.x >> shift) & 255;
      out[poff + delta[d] + p] = pr;
    }
  }
}

__global__ __launch_bounds__(256) void build_rp(const int2* __restrict__ A, int* __restrict__ rp) {
  int s = blockIdx.y;
  int len = SLEN[s];
  int j = blockIdx.x * 256 + threadIdx.x;
  if (j >= len) return;
  size_t poff = SPOFF[s];
  int ro = SEG_RO[s];
  int k = A[poff + j].x;
  int kprev = (j == 0) ? -1 : A[poff + j - 1].x;
  for (int d = kprev + 1; d <= k; ++d) rp[ro + d] = j;
  if (j == len - 1) {
    int n = SEG_N[s];
    for (int d = k + 1; d <= n; ++d) rp[ro + d] = len;
  }
}

// ---------------- atom mean aggregation: 2 chems/wave, 32-lane groups, float4 ----------------

__global__ __launch_bounds__(256) void mean_atoms(const float* __restrict__ x_atom,
                                                  const int* __restrict__ rp,
                                                  const int2* __restrict__ pairs,
                                                  float* __restrict__ Mean) {
  int wave = (blockIdx.x * blockDim.x + threadIdx.x) >> 6;
  int lane = threadIdx.x & 63;
  int g = lane >> 5, l32 = lane & 31;        // group (0/1), lane-in-group
  int chem = wave * 2 + g;
  if (chem >= 20000) return;
  int b = rp[chem], e = rp[chem + 1];
  float4 s = make_float4(0.f, 0.f, 0.f, 0.f);
  for (int j = b; j < e; ++j) {              // divergent across groups: exec-masked
    int a = pairs[j].y;
    float4 v = *(const float4*)(x_atom + (size_t)a * H + l32 * 4);
    s.x += v.x; s.y += v.y; s.z += v.z; s.w += v.w;
  }
  float inv = 1.0f / fmaxf((float)(e - b), 1.0f);
  float4 o; o.x = s.x * inv; o.y = s.y * inv; o.z = s.z * inv; o.w = s.w * inv;
  *(float4*)(Mean + (size_t)chem * H + l32 * 4) = o;
}

// ---------------- fp32 projection (used once, for W_mol): Y = X @ W + Res ----------------

__global__ __launch_bounds__(256) void proj_kernel(
    const float* __restrict__ X, const float* __restrict__ W,
    const float* __restrict__ Res, float* __restrict__ Y, int N) {
  int r0 = blockIdx.x * 64;
  if (r0 >= N) return;
  __shared__ float Xs[64][132];
  int tid = threadIdx.x;
#pragma unroll
  for (int i = 0; i < 8; ++i) {
    int f = tid + 256 * i;
    int row = f >> 5, c4 = (f & 31) << 2;
    float4 v = make_float4(0.f, 0.f, 0.f, 0.f);
    if (r0 + row < N) v = *(const float4*)(X + (size_t)(r0 + row) * H + c4);
    *(float4*)&Xs[row][c4] = v;
  }
  __syncthreads();
  int trow = tid >> 5, tcol = tid & 31;
  float acc[8][4] = {};
#pragma unroll 4
  for (int k = 0; k < 128; ++k) {
    float4 w = *(const float4*)(W + k * H + tcol * 4);
#pragma unroll
    for (int i = 0; i < 8; ++i) {
      float xv = Xs[trow * 8 + i][k];
      acc[i][0] = fmaf(xv, w.x, acc[i][0]);
      acc[i][1] = fmaf(xv, w.y, acc[i][1]);
      acc[i][2] = fmaf(xv, w.z, acc[i][2]);
      acc[i][3] = fmaf(xv, w.w, acc[i][3]);
    }
  }
#pragma unroll
  for (int i = 0; i < 8; ++i) {
    int row = r0 + trow * 8 + i;
    if (row < N) {
      float4 rv = *(const float4*)(Res + (size_t)row * H + tcol * 4);
      float4 ov;
      ov.x = acc[i][0] + rv.x; ov.y = acc[i][1] + rv.y;
      ov.z = acc[i][2] + rv.z; ov.w = acc[i][3] + rv.w;
      *(float4*)(Y + (size_t)row * H + tcol * 4) = ov;
    }
  }
}

// ---------------- converts ----------------

__global__ __launch_bounds__(256) void conv_xs(const float* __restrict__ xs,
                                               const float* __restrict__ x_gene,
                                               const float* __restrict__ x_assay,
                                               u16* __restrict__ xsb) {
  int idx = (blockIdx.x * 256 + threadIdx.x) * 4;
  if (idx >= 50000 * H) return;
  int row = idx >> 7;
  const float* src;
  if (row < 20000)      src = xs + idx;
  else if (row < 40000) src = x_gene + (idx - 20000 * H);
  else                  src = x_assay + (idx - 40000 * H);
  float4 v = *(const float4*)src;
  u32 p0 = (u32)f2bf(v.x) | ((u32)f2bf(v.y) << 16);
  u32 p1 = (u32)f2bf(v.z) | ((u32)f2bf(v.w) << 16);
  u32* o = (u32*)(xsb + idx);
  o[0] = p0; o[1] = p1;
}

// WB[(mat*2+side)][n][k] = bf16( (side?Wr:Wl)[mat][k][n] )
__global__ __launch_bounds__(256) void conv_weights(const float* __restrict__ Wl,
                                                    const float* __restrict__ Wr,
                                                    u16* __restrict__ WB) {
  int mat = blockIdx.x;      // 0..25
  int side = blockIdx.y;     // 0..1
  const float* W = (side ? Wr : Wl) + (size_t)mat * H * H;
  u16* O = WB + ((size_t)mat * 2 + side) * H * H;
  for (int f = threadIdx.x; f < H * H; f += 256) {
    int n = f >> 7, k = f & 127;
    O[f] = f2bf(W[k * H + n]);
  }
}

// ---------------- batched bf16 MFMA projection: all 26 GEMMs of one layer ----------------

__global__ __launch_bounds__(256) void proj_mfma(
    const u16* __restrict__ xsb, const u16* __restrict__ WB,
    const float* __restrict__ bl, const float* __restrict__ br,
    u16* __restrict__ XLb, u16* __restrict__ XRb, int layer) {
  int by = blockIdx.y;               // 0..25
  int r = by >> 1, side = by & 1;
  int typ = side ? DST_T[r] : SRC_T[r];
  int N = NODE_N[typ];
  int r0 = blockIdx.x * 64;
  if (r0 >= N) return;
  const u16* X = xsb + (size_t)TYPE_OFF[typ] * H;
  const u16* W = WB + ((size_t)(layer * NREL + r) * 2 + side) * H * H;
  const float* bias = (side ? br : bl) + (size_t)(layer * NREL + r) * H;
  u16* Y = side ? (XRb + (size_t)XOFF_D[r] * H) : (XLb + (size_t)XOFF_S[r] * H);

  __shared__ u16 Xs[64 * 136];
  __shared__ u16 Ws[128 * 136];
  int tid = threadIdx.x;
#pragma unroll
  for (int i = 0; i < 4; ++i) {
    int f = tid + 256 * i;
    int row = f >> 4, seg = f & 15;
    ushort8 v = {};
    if (r0 + row < N) v = *(const ushort8*)(X + (size_t)(r0 + row) * H + seg * 8);
    *(ushort8*)(Xs + row * 136 + seg * 8) = v;
  }
#pragma unroll
  for (int i = 0; i < 8; ++i) {
    int f = tid + 256 * i;
    int row = f >> 4, seg = f & 15;
    *(ushort8*)(Ws + row * 136 + seg * 8) = *(const ushort8*)(W + row * H + seg * 8);
  }
  __syncthreads();

  int w = tid >> 6, lane = tid & 63;
  int g = lane >> 4, l16 = lane & 15;
  floatx4 acc[4][2] = {};
#pragma unroll
  for (int kt = 0; kt < 4; ++kt) {
    int k0 = kt * 32 + g * 8;
    short8 a[4], b[2];
#pragma unroll
    for (int rt = 0; rt < 4; ++rt) a[rt] = *(const short8*)(Xs + (rt * 16 + l16) * 136 + k0);
#pragma unroll
    for (int ct = 0; ct < 2; ++ct) b[ct] = *(const short8*)(Ws + (w * 32 + ct * 16 + l16) * 136 + k0);
#pragma unroll
    for (int rt = 0; rt < 4; ++rt)
#pragma unroll
      for (int ct = 0; ct < 2; ++ct)
        acc[rt][ct] = __builtin_amdgcn_mfma_f32_16x16x32_bf16(a[rt], b[ct], acc[rt][ct], 0, 0, 0);
  }
  __syncthreads();
  float bv0 = bias[w * 32 + l16];
  float bv1 = bias[w * 32 + 16 + l16];
#pragma unroll
  for (int rt = 0; rt < 4; ++rt)
#pragma unroll
    for (int ct = 0; ct < 2; ++ct) {
      float bv = ct ? bv1 : bv0;
      int col = w * 32 + ct * 16 + l16;
#pragma unroll
      for (int reg = 0; reg < 4; ++reg) {
        int row = rt * 16 + g * 4 + reg;
        Xs[row * 136 + col] = f2bf(acc[rt][ct][reg] + bv);
      }
    }
  __syncthreads();
#pragma unroll
  for (int i = 0; i < 4; ++i) {
    int f = tid + 256 * i;
    int row = f >> 4, seg = f & 15;
    if (r0 + row < N)
      *(ushort8*)(Y + (size_t)(r0 + row) * H + seg * 8) = *(const ushort8*)(Xs + row * 136 + seg * 8);
  }
}

// ---------------- fused GATv2 edge pass: 4 dsts per wave, 16-lane groups, 8 ch/lane ----------------

__global__ __launch_bounds__(256) void gat_fused(
    const u16* __restrict__ XLb, const u16* __restrict__ XRb,
    const int* __restrict__ rp, const int2* __restrict__ A,
    const float* __restrict__ att_a, const float* __restrict__ cbv,
    float* __restrict__ agg, int layer, int dt) {
  int wave = (blockIdx.x * blockDim.x + threadIdx.x) >> 6;
  int lane = threadIdx.x & 63;
  int g = lane >> 4, l16 = lane & 15;
  int d = wave * 4 + g;
  int Nd = NODE_N[dt];
  bool dv = d < Nd;
  int dd = dv ? d : Nd - 1;
  float o[8] = {};
  int nr = NREL_OF[dt];
  for (int rr = 0; rr < nr; ++rr) {
    int r = RELS_OF[dt][rr];
    size_t wi = (size_t)layer * NREL + r;
    const u16* XL = XLb + (size_t)XOFF_S[r] * H;
    const u16* XR = XRb + (size_t)XOFF_D[r] * H;
    // per-dst xr (8 bf16 channels), attention vector (8 fp32)
    ushort8 uxr = *(const ushort8*)(XR + (size_t)dd * H + l16 * 8);
    float xr[8];
#pragma unroll
    for (int c = 0; c < 8; ++c) xr[c] = bf2f((u16)uxr[c]);
    float4 a0 = *(const float4*)(att_a + wi * H + l16 * 8);
    float4 a1 = *(const float4*)(att_a + wi * H + l16 * 8 + 4);
    float av[8] = {a0.x, a0.y, a0.z, a0.w, a1.x, a1.y, a1.z, a1.w};
    const int* rpr = rp + SEG_RO[r + 1];
    const int2* pe = A + SPOFF[r + 1];
    int b = dv ? rpr[dd] : 0;
    int e = dv ? rpr[dd + 1] : 0;
    float m = -1e30f, s = 0.f;
    float V[8] = {};
    for (int j = b; j < e; ++j) {            // divergent across groups: exec-masked
      int src = pe[j].y;
      ushort8 uxl = *(const ushort8*)(XL + (size_t)src * H + l16 * 8);
      float xl[8];
      float t = 0.f;
#pragma unroll
      for (int c = 0; c < 8; ++c) {
        xl[c] = bf2f((u16)uxl[c]);
        float v = xl[c] + xr[c];
        float lr = v > 0.f ? v : 0.2f * v;
        t = fmaf(av[c], lr, t);
      }
      t += __shfl_xor(t, 1, 64);
      t += __shfl_xor(t, 2, 64);
      t += __shfl_xor(t, 4, 64);
      t += __shfl_xor(t, 8, 64);             // 16-lane group sum
      float nm = fmaxf(m, t);
      float sc = __expf(m - nm);             // first edge: exp(-1e30 - t) -> 0, no NaN
      float wgt = __expf(t - nm);
      s = s * sc + wgt;
#pragma unroll
      for (int c = 0; c < 8; ++c) V[c] = V[c] * sc + wgt * xl[c];
      m = nm;
    }
    if (s > 0.f) {
      float inv = 1.0f / s;
#pragma unroll
      for (int c = 0; c < 8; ++c) o[c] += V[c] * inv;
    }
    float4 c0 = *(const float4*)(cbv + wi * H + l16 * 8);
    float4 c1 = *(const float4*)(cbv + wi * H + l16 * 8 + 4);
    o[0] += c0.x; o[1] += c0.y; o[2] += c0.z; o[3] += c0.w;
    o[4] += c1.x; o[5] += c1.y; o[6] += c1.z; o[7] += c1.w;
  }
  if (dv) {
    float* ap = agg + (size_t)(TYPE_OFF[dt] + d) * H + l16 * 8;
    *(float4*)ap       = make_float4(o[0], o[1], o[2], o[3]);
    *(float4*)(ap + 4) = make_float4(o[4], o[5], o[6], o[7]);
  }
}

// ---------------- LayerNorm + ReLU (fp32 in, bf16 out) ----------------

__global__ __launch_bounds__(256) void ln_relu_kernel(const float* __restrict__ agg,
                                                      const float* __restrict__ g,
                                                      const float* __restrict__ b,
                                                      u16* __restrict__ xsb) {
  int row = (blockIdx.x * blockDim.x + threadIdx.x) >> 6;
  int lane = threadIdx.x & 63;
  if (row >= 50000) return;
  int t = row < 20000 ? 0 : (row < 40000 ? 1 : 2);
  float2 x = *(const float2*)(agg + (size_t)row * H + 2 * lane);
  float mu = wave_reduce_sum(x.x + x.y) * (1.f / 128.f);
  float d0 = x.x - mu, d1 = x.y - mu;
  float var = wave_reduce_sum(d0 * d0 + d1 * d1) * (1.f / 128.f);
  float inv = 1.0f / sqrtf(var + 1e-5f);
  float2 gg = *(const float2*)(g + t * H + 2 * lane);
  float2 bb = *(const float2*)(b + t * H + 2 * lane);
  float o0 = fmaxf(d0 * inv * gg.x + bb.x, 0.f);
  float o1 = fmaxf(d1 * inv * gg.y + bb.y, 0.f);
  u32 pk = (u32)f2bf(o0) | ((u32)f2bf(o1) << 16);
  *(u32*)(xsb + (size_t)row * H + 2 * lane) = pk;
}

// ---------------- prediction head: bf16[20000,128] @ fp32[128,2] + bp ----------------

__global__ __launch_bounds__(256) void pred_kernel(const u16* __restrict__ xsb,
                                                   const float* __restrict__ Wp,
                                                   const float* __restrict__ bp,
                                                   float* __restrict__ out) {
  int row = (blockIdx.x * blockDim.x + threadIdx.x) >> 6;
  int lane = threadIdx.x & 63;
  if (row >= 20000) return;
  u32 u = *(const u32*)(xsb + (size_t)row * H + 2 * lane);
  float x0 = bflo(u), x1 = bfhi(u);
  float4 w = *(const float4*)(Wp + 4 * lane);
  float pA = x0 * w.x + x1 * w.z;
  float pB = x0 * w.y + x1 * w.w;
  pA = wave_reduce_sum(pA);
  pB = wave_reduce_sum(pB);
  if (lane == 0) {
    out[(size_t)row * 2 + 0] = pA + bp[0];
    out[(size_t)row * 2 + 1] = pB + bp[1];
  }
}

// ---------------- launch ----------------

extern "C" void kernel_launch(void* const* d_in, const int* in_sizes, int n_in,
                              void* d_out, int out_size, void* d_ws, size_t ws_size,
                              hipStream_t stream) {
  (void)in_sizes; (void)n_in; (void)out_size; (void)ws_size;
  const float* x_atom  = (const float*)d_in[0];
  const float* x_chem  = (const float*)d_in[1];
  const float* x_gene  = (const float*)d_in[2];
  const float* x_assay = (const float*)d_in[3];
  const float* W_mol   = (const float*)d_in[4];
  const float* Wl      = (const float*)d_in[5];
  const float* Wr      = (const float*)d_in[6];
  const float* bl      = (const float*)d_in[7];
  const float* br      = (const float*)d_in[8];
  const float* att_a   = (const float*)d_in[9];
  const float* cb      = (const float*)d_in[10];
  const float* ln_g    = (const float*)d_in[11];
  const float* ln_b    = (const float*)d_in[12];
  const float* Wp      = (const float*)d_in[13];
  const float* bp      = (const float*)d_in[14];
  const int*   hyper   = (const int*)d_in[15];
  const int*   ei      = (const int*)d_in[16];
  float* out = (float*)d_out;

  float* ws = (float*)d_ws;
  size_t o = 0;
  float* xs   = ws + o; o += (size_t)50000 * H;
  float* agg  = ws + o; o += (size_t)50000 * H;
  float* Mean = ws + o; o += (size_t)20000 * H;
  int2*  A    = (int2*)(ws + o); o += (size_t)2 * NPAIR;
  int2*  Bp2  = (int2*)(ws + o); o += (size_t)2 * NPAIR;
  int*   rp   = (int*)(ws + o); o += RP_TOTAL;
  int*   bh   = (int*)(ws + o); o += BH_TOTAL;
  u16*   xsb  = (u16*)(ws + o); o += (size_t)50000 * H / 2;
  u16*   WB   = (u16*)(ws + o); o += (size_t)52 * H * H / 2;
  u16*   XLb  = (u16*)(ws + o); o += (size_t)XTOT * H / 2;
  u16*   XRb  = (u16*)(ws + o); o += (size_t)XTOT * H / 2;

  dim3 b256(256);

  // ---- CSR build via stable radix sort (no global atomics) ----
  radix_init<<<dim3(2344, SEGS), b256, 0, stream>>>(hyper, ei, A);
  radix_count<<<dim3(147, SEGS), b256, 0, stream>>>(A, bh, 0);
  radix_scan<<<SEGS, b256, 0, stream>>>(bh);
  radix_scatter<<<dim3(147, SEGS), b256, 0, stream>>>(A, Bp2, bh, 0);
  radix_count<<<dim3(147, SEGS), b256, 0, stream>>>(Bp2, bh, 8);
  radix_scan<<<SEGS, b256, 0, stream>>>(bh);
  radix_scatter<<<dim3(147, SEGS), b256, 0, stream>>>(Bp2, A, bh, 8);
  build_rp<<<dim3(2344, SEGS), b256, 0, stream>>>(A, rp);

  // ---- xs[chem] = segment_mean(x_atom) @ W_mol + x_chem; xsb = bf16 features ----
  mean_atoms<<<dim3(20000 / 8), b256, 0, stream>>>(x_atom, rp, A, Mean);
  proj_kernel<<<dim3(313), b256, 0, stream>>>(Mean, W_mol, x_chem, xs, 20000);
  conv_xs<<<dim3(6250), b256, 0, stream>>>(xs, x_gene, x_assay, xsb);
  conv_weights<<<dim3(26, 2), b256, 0, stream>>>(Wl, Wr, WB);

  for (int l = 0; l < NLAYER; ++l) {
    proj_mfma<<<dim3(313, 26), b256, 0, stream>>>(xsb, WB, bl, br, XLb, XRb, l);
    for (int dt = 0; dt < 3; ++dt)
      gat_fused<<<dim3((NODE_N[dt] + 15) / 16), b256, 0, stream>>>(
          XLb, XRb, rp, A, att_a, cb, agg, l, dt);
    ln_relu_kernel<<<dim3(50000 / 4), b256, 0, stream>>>(agg, ln_g + l * 3 * H, ln_b + l * 3 * H, xsb);
  }
  pred_kernel<<<dim3(20000 / 4), b256, 0, stream>>>(xsb, Wp, bp, out);
}

// Round 5
// 1477.423 us; speedup vs baseline: 2.4206x; 1.1576x over previous
//
#include <hip/hip_runtime.h>
#include <math.h>

#define H 128
#define NLAYER 2
#define EDG 400000
#define NATOM 600000
#define NREL 13
#define SEGS 14
#define RDX 256
#define TILE 4096

typedef unsigned short u16;
typedef unsigned int u32;
using short8  = __attribute__((ext_vector_type(8))) short;
using ushort8 = __attribute__((ext_vector_type(8))) unsigned short;
using floatx4 = __attribute__((ext_vector_type(4))) float;

static constexpr int NODE_N[3]   = {20000, 20000, 10000};
static constexpr int TYPE_OFF[3] = {0, 20000, 40000};
static constexpr int SRC_T[NREL] = {0,0,0,0,0,2,1,2,2,1,1,1,1};
static constexpr int DST_T[NREL] = {2,2,1,1,1,1,1,0,0,0,0,0,2};

// relations grouped by dst type (for fused GAT)
static constexpr int NREL_OF[3]    = {5, 5, 3};
static constexpr int RELS_OF[3][5] = {{7,8,9,10,11},{2,3,4,5,6},{0,1,12}};

// per-relation row offsets into the XLb / XRb projection tables
static constexpr int XOFF_S[NREL] = {0,20000,40000,60000,80000,100000,110000,130000,140000,150000,170000,190000,210000};
static constexpr int XOFF_D[NREL] = {0,10000,20000,40000,60000,80000,100000,120000,140000,160000,180000,200000,220000};
#define XTOT 230000

// segments: 0 = atoms (int2 pairs, key bits [0,15)), 1..13 = edges (u32 packed, key bits [15,30))
static constexpr int SEG_N[SEGS]  = {20000,10000,10000,20000,20000,20000,20000,20000,20000,20000,20000,20000,20000,10000};
static constexpr int SEG_RO[SEGS] = {0,20001,30002,40003,60004,80005,100006,120007,140008,160009,180010,200011,220012,240013};
#define RP_TOTAL 250016

static constexpr int    SLEN[SEGS]   = {600000,EDG,EDG,EDG,EDG,EDG,EDG,EDG,EDG,EDG,EDG,EDG,EDG,EDG};
static constexpr int    RNB[SEGS]    = {147,98,98,98,98,98,98,98,98,98,98,98,98,98};   // ceil(len/TILE)
static constexpr int    RBHOFF[SEGS] = {0,37632,62720,87808,112896,137984,163072,188160,213248,238336,263424,288512,313600,338688};
#define BH_TOTAL 363776

__device__ __forceinline__ float wave_reduce_sum(float v) {
#pragma unroll
  for (int off = 32; off > 0; off >>= 1) v += __shfl_xor(v, off, 64);
  return v;
}

__device__ __forceinline__ u16 f2bf(float f) {
  union { float f; u32 u; } c; c.f = f;
  u32 u = c.u + 0x7fffu + ((c.u >> 16) & 1u);   // RNE
  return (u16)(u >> 16);
}
__device__ __forceinline__ float bf2f(u16 h) { union { u32 i; float f; } c; c.i = (u32)h << 16; return c.f; }
__device__ __forceinline__ float bflo(u32 u) { union { u32 i; float f; } c; c.i = u << 16; return c.f; }
__device__ __forceinline__ float bfhi(u32 u) { union { u32 i; float f; } c; c.i = u & 0xffff0000u; return c.f; }

__device__ __forceinline__ int digof(u32 v, int shift) { return (int)((v >> shift) & 255u); }
__device__ __forceinline__ int digof(int2 v, int shift) { return (v.x >> shift) & 255; }

// ---------------- radix sort (2 passes, stable, no global atomics; templated on element) ----------------

__global__ __launch_bounds__(256) void radix_init_a(const int* __restrict__ hyper, int2* __restrict__ Aa) {
  int i = blockIdx.x * 256 + threadIdx.x;
  if (i >= NATOM) return;
  Aa[i] = make_int2(hyper[i], i);
}

__global__ __launch_bounds__(256) void radix_init_e(const int* __restrict__ ei, u32* __restrict__ Ae) {
  int r = blockIdx.y;
  int i = blockIdx.x * 256 + threadIdx.x;
  if (i >= EDG) return;
  u32 src = (u32)ei[(size_t)(r * 2) * EDG + i];
  u32 dst = (u32)ei[(size_t)(r * 2 + 1) * EDG + i];
  Ae[(size_t)r * EDG + i] = (dst << 15) | src;
}

template <typename T>
__global__ __launch_bounds__(256) void radix_count_t(const T* __restrict__ in,
                                                     int* __restrict__ bh, int shift, int seg0) {
  int s = seg0 + blockIdx.y, bx = blockIdx.x;
  int nb = RNB[s];
  __shared__ int h[RDX];
  int t = threadIdx.x;
  h[t] = 0;
  __syncthreads();
  int len = SLEN[s];
  size_t poff = (s == 0) ? 0 : (size_t)(s - 1) * EDG;
#pragma unroll
  for (int i = 0; i < 16; ++i) {
    int p = bx * TILE + i * 256 + t;
    if (p < len) atomicAdd(&h[digof(in[poff + p], shift)], 1);
  }
  __syncthreads();
  bh[RBHOFF[s] + t * nb + bx] = h[t];
}

__global__ __launch_bounds__(256) void radix_scan(int* __restrict__ bh) {
  int s = blockIdx.x;
  int total = RNB[s] * RDX;
  int off = RBHOFF[s];
  __shared__ int sums[256];
  int t = threadIdx.x;
  int chunk = (total + 255) >> 8;
  int b = t * chunk, e = min(b + chunk, total);
  int acc = 0;
  for (int i = b; i < e; ++i) acc += bh[off + i];
  sums[t] = acc;
  __syncthreads();
  for (int o2 = 1; o2 < 256; o2 <<= 1) {
    int v = (t >= o2) ? sums[t - o2] : 0;
    __syncthreads();
    sums[t] += v;
    __syncthreads();
  }
  int pre = t ? sums[t - 1] : 0;
  for (int i = b; i < e; ++i) { int c = bh[off + i]; bh[off + i] = pre; pre += c; }
}

template <typename T>
__global__ __launch_bounds__(256) void radix_scat_t(const T* __restrict__ in,
                                                    T* __restrict__ out,
                                                    const int* __restrict__ bh, int shift, int seg0) {
  int s = seg0 + blockIdx.y, bx = blockIdx.x;
  int nb = RNB[s];
  __shared__ T stg[TILE];
  __shared__ int wc[4][RDX];
  __shared__ int pw[4][RDX];
  __shared__ int basev[RDX];
  __shared__ int lstart[RDX];
  __shared__ int delta[RDX];
  int t = threadIdx.x;
  int lane = t & 63, w = t >> 6;
  unsigned long long lmask = (1ull << lane) - 1ull;
  int len = SLEN[s];
  size_t poff = (s == 0) ? 0 : (size_t)(s - 1) * EDG;
  T kv[16]; int dg[16]; int rk[16];
  basev[t] = 0;
#pragma unroll
  for (int i = 0; i < 16; ++i) {
    int p = bx * TILE + i * 256 + t;
    kv[i] = (p < len) ? in[poff + p] : T{};
  }
  __syncthreads();
  for (int i = 0; i < 16; ++i) {
    int p = bx * TILE + i * 256 + t;
    bool valid = p < len;
    int d = digof(kv[i], shift);
    wc[0][t] = 0; wc[1][t] = 0; wc[2][t] = 0; wc[3][t] = 0;
    __syncthreads();
    unsigned long long m = __ballot(valid);
#pragma unroll
    for (int b2 = 0; b2 < 8; ++b2) {
      unsigned long long bal = __ballot((d >> b2) & 1);
      m &= ((d >> b2) & 1) ? bal : ~bal;
    }
    int riw = __popcll(m & lmask);
    if (valid && riw == 0) wc[w][d] = __popcll(m);
    __syncthreads();
    int s0 = 0;
#pragma unroll
    for (int ww = 0; ww < 4; ++ww) { pw[ww][t] = s0; s0 += wc[ww][t]; }
    __syncthreads();
    dg[i] = d;
    rk[i] = basev[d] + pw[w][d] + riw;
    __syncthreads();
    basev[t] += s0;
    __syncthreads();
  }
  int tot = basev[t];
  pw[0][t] = tot;
  __syncthreads();
  for (int o2 = 1; o2 < 256; o2 <<= 1) {
    int v = (t >= o2) ? pw[0][t - o2] : 0;
    __syncthreads();
    pw[0][t] += v;
    __syncthreads();
  }
  int ls = pw[0][t] - tot;
  lstart[t] = ls;
  delta[t] = bh[RBHOFF[s] + t * nb + bx] - ls;
  __syncthreads();
#pragma unroll
  for (int i = 0; i < 16; ++i) {
    int p = bx * TILE + i * 256 + t;
    if (p < len) stg[lstart[dg[i]] + rk[i]] = kv[i];
  }
  __syncthreads();
  int vc = min(len - bx * TILE, TILE);
#pragma unroll
  for (int i = 0; i < 16; ++i) {
    int p = i * 256 + t;
    if (p < vc) {
      T pr = stg[p];
      int d = digof(pr, shift);
      out[poff + delta[d] + p] = pr;
    }
  }
}

__global__ __launch_bounds__(256) void build_rp_a(const int2* __restrict__ Aa, int* __restrict__ rp) {
  int j = blockIdx.x * 256 + threadIdx.x;
  if (j >= NATOM) return;
  int k = Aa[j].x;
  int kprev = (j == 0) ? -1 : Aa[j - 1].x;
  for (int d = kprev + 1; d <= k; ++d) rp[d] = j;
  if (j == NATOM - 1)
    for (int d = k + 1; d <= 20000; ++d) rp[d] = NATOM;
}

__global__ __launch_bounds__(256) void build_rp_e(const u32* __restrict__ Ae, int* __restrict__ rp) {
  int r = blockIdx.y;
  int j = blockIdx.x * 256 + threadIdx.x;
  if (j >= EDG) return;
  const u32* Ar = Ae + (size_t)r * EDG;
  int ro = SEG_RO[r + 1];
  int n = SEG_N[r + 1];
  int k = (int)(Ar[j] >> 15);
  int kprev = (j == 0) ? -1 : (int)(Ar[j - 1] >> 15);
  for (int d = kprev + 1; d <= k; ++d) rp[ro + d] = j;
  if (j == EDG - 1)
    for (int d = k + 1; d <= n; ++d) rp[ro + d] = EDG;
}

// ---------------- atom mean aggregation: 2 chems/wave, 32-lane groups, float4 ----------------

__global__ __launch_bounds__(256) void mean_atoms(const float* __restrict__ x_atom,
                                                  const int* __restrict__ rp,
                                                  const int2* __restrict__ pairs,
                                                  float* __restrict__ Mean) {
  int wave = (blockIdx.x * blockDim.x + threadIdx.x) >> 6;
  int lane = threadIdx.x & 63;
  int g = lane >> 5, l32 = lane & 31;
  int chem = wave * 2 + g;
  if (chem >= 20000) return;
  int b = rp[chem], e = rp[chem + 1];
  float4 s = make_float4(0.f, 0.f, 0.f, 0.f);
  for (int j = b; j < e; ++j) {
    int a = pairs[j].y;
    float4 v = *(const float4*)(x_atom + (size_t)a * H + l32 * 4);
    s.x += v.x; s.y += v.y; s.z += v.z; s.w += v.w;
  }
  float inv = 1.0f / fmaxf((float)(e - b), 1.0f);
  float4 o; o.x = s.x * inv; o.y = s.y * inv; o.z = s.z * inv; o.w = s.w * inv;
  *(float4*)(Mean + (size_t)chem * H + l32 * 4) = o;
}

// ---------------- fp32 projection (W_mol): xsb[chem] = bf16(Mean @ W + x_chem) ----------------

__global__ __launch_bounds__(256) void proj_kernel(
    const float* __restrict__ X, const float* __restrict__ W,
    const float* __restrict__ Res, u16* __restrict__ Yb, int N) {
  int r0 = blockIdx.x * 64;
  if (r0 >= N) return;
  __shared__ float Xs[64][132];
  int tid = threadIdx.x;
#pragma unroll
  for (int i = 0; i < 8; ++i) {
    int f = tid + 256 * i;
    int row = f >> 5, c4 = (f & 31) << 2;
    float4 v = make_float4(0.f, 0.f, 0.f, 0.f);
    if (r0 + row < N) v = *(const float4*)(X + (size_t)(r0 + row) * H + c4);
    *(float4*)&Xs[row][c4] = v;
  }
  __syncthreads();
  int trow = tid >> 5, tcol = tid & 31;
  float acc[8][4] = {};
#pragma unroll 4
  for (int k = 0; k < 128; ++k) {
    float4 w = *(const float4*)(W + k * H + tcol * 4);
#pragma unroll
    for (int i = 0; i < 8; ++i) {
      float xv = Xs[trow * 8 + i][k];
      acc[i][0] = fmaf(xv, w.x, acc[i][0]);
      acc[i][1] = fmaf(xv, w.y, acc[i][1]);
      acc[i][2] = fmaf(xv, w.z, acc[i][2]);
      acc[i][3] = fmaf(xv, w.w, acc[i][3]);
    }
  }
#pragma unroll
  for (int i = 0; i < 8; ++i) {
    int row = r0 + trow * 8 + i;
    if (row < N) {
      float4 rv = *(const float4*)(Res + (size_t)row * H + tcol * 4);
      u32 lo = (u32)f2bf(acc[i][0] + rv.x) | ((u32)f2bf(acc[i][1] + rv.y) << 16);
      u32 hi = (u32)f2bf(acc[i][2] + rv.z) | ((u32)f2bf(acc[i][3] + rv.w) << 16);
      *(uint2*)(Yb + (size_t)row * H + tcol * 4) = make_uint2(lo, hi);
    }
  }
}

// ---------------- converts ----------------

// xsb rows [20000,50000) = bf16([x_gene | x_assay])
__global__ __launch_bounds__(256) void conv_xs(const float* __restrict__ x_gene,
                                               const float* __restrict__ x_assay,
                                               u16* __restrict__ xsb) {
  int idx = 20000 * H + (blockIdx.x * 256 + threadIdx.x) * 4;
  if (idx >= 50000 * H) return;
  int row = idx >> 7;
  const float* src = (row < 40000) ? x_gene + (idx - 20000 * H) : x_assay + (idx - 40000 * H);
  float4 v = *(const float4*)src;
  u32 p0 = (u32)f2bf(v.x) | ((u32)f2bf(v.y) << 16);
  u32 p1 = (u32)f2bf(v.z) | ((u32)f2bf(v.w) << 16);
  u32* o = (u32*)(xsb + idx);
  o[0] = p0; o[1] = p1;
}

// WB[(mat*2+side)][n][k] = bf16( (side?Wr:Wl)[mat][k][n] )
__global__ __launch_bounds__(256) void conv_weights(const float* __restrict__ Wl,
                                                    const float* __restrict__ Wr,
                                                    u16* __restrict__ WB) {
  int mat = blockIdx.x;
  int side = blockIdx.y;
  const float* W = (side ? Wr : Wl) + (size_t)mat * H * H;
  u16* O = WB + ((size_t)mat * 2 + side) * H * H;
  for (int f = threadIdx.x; f < H * H; f += 256) {
    int n = f >> 7, k = f & 127;
    O[f] = f2bf(W[k * H + n]);
  }
}

// ---------------- batched bf16 MFMA projection: all 26 GEMMs of one layer ----------------

__global__ __launch_bounds__(256) void proj_mfma(
    const u16* __restrict__ xsb, const u16* __restrict__ WB,
    const float* __restrict__ bl, const float* __restrict__ br,
    u16* __restrict__ XLb, u16* __restrict__ XRb, int layer) {
  int by = blockIdx.y;
  int r = by >> 1, side = by & 1;
  int typ = side ? DST_T[r] : SRC_T[r];
  int N = NODE_N[typ];
  int r0 = blockIdx.x * 64;
  if (r0 >= N) return;
  const u16* X = xsb + (size_t)TYPE_OFF[typ] * H;
  const u16* W = WB + ((size_t)(layer * NREL + r) * 2 + side) * H * H;
  const float* bias = (side ? br : bl) + (size_t)(layer * NREL + r) * H;
  u16* Y = side ? (XRb + (size_t)XOFF_D[r] * H) : (XLb + (size_t)XOFF_S[r] * H);

  __shared__ u16 Xs[64 * 136];
  __shared__ u16 Ws[128 * 136];
  int tid = threadIdx.x;
#pragma unroll
  for (int i = 0; i < 4; ++i) {
    int f = tid + 256 * i;
    int row = f >> 4, seg = f & 15;
    ushort8 v = {};
    if (r0 + row < N) v = *(const ushort8*)(X + (size_t)(r0 + row) * H + seg * 8);
    *(ushort8*)(Xs + row * 136 + seg * 8) = v;
  }
#pragma unroll
  for (int i = 0; i < 8; ++i) {
    int f = tid + 256 * i;
    int row = f >> 4, seg = f & 15;
    *(ushort8*)(Ws + row * 136 + seg * 8) = *(const ushort8*)(W + row * H + seg * 8);
  }
  __syncthreads();

  int w = tid >> 6, lane = tid & 63;
  int g = lane >> 4, l16 = lane & 15;
  floatx4 acc[4][2] = {};
#pragma unroll
  for (int kt = 0; kt < 4; ++kt) {
    int k0 = kt * 32 + g * 8;
    short8 a[4], b[2];
#pragma unroll
    for (int rt = 0; rt < 4; ++rt) a[rt] = *(const short8*)(Xs + (rt * 16 + l16) * 136 + k0);
#pragma unroll
    for (int ct = 0; ct < 2; ++ct) b[ct] = *(const short8*)(Ws + (w * 32 + ct * 16 + l16) * 136 + k0);
#pragma unroll
    for (int rt = 0; rt < 4; ++rt)
#pragma unroll
      for (int ct = 0; ct < 2; ++ct)
        acc[rt][ct] = __builtin_amdgcn_mfma_f32_16x16x32_bf16(a[rt], b[ct], acc[rt][ct], 0, 0, 0);
  }
  __syncthreads();
  float bv0 = bias[w * 32 + l16];
  float bv1 = bias[w * 32 + 16 + l16];
#pragma unroll
  for (int rt = 0; rt < 4; ++rt)
#pragma unroll
    for (int ct = 0; ct < 2; ++ct) {
      float bv = ct ? bv1 : bv0;
      int col = w * 32 + ct * 16 + l16;
#pragma unroll
      for (int reg = 0; reg < 4; ++reg) {
        int row = rt * 16 + g * 4 + reg;
        Xs[row * 136 + col] = f2bf(acc[rt][ct][reg] + bv);
      }
    }
  __syncthreads();
#pragma unroll
  for (int i = 0; i < 4; ++i) {
    int f = tid + 256 * i;
    int row = f >> 4, seg = f & 15;
    if (r0 + row < N)
      *(ushort8*)(Y + (size_t)(r0 + row) * H + seg * 8) = *(const ushort8*)(Xs + row * 136 + seg * 8);
  }
}

// ---------------- fused GATv2: all 50000 dsts, 4/wave, 16-lane groups, 2-edge unroll ----------------

__global__ __launch_bounds__(256) void gat_fused(
    const u16* __restrict__ XLb, const u16* __restrict__ XRb,
    const int* __restrict__ rp, const u32* __restrict__ Ae,
    const float* __restrict__ att_a, const float* __restrict__ cbv,
    float* __restrict__ agg, int layer) {
  int wave = (blockIdx.x * blockDim.x + threadIdx.x) >> 6;
  int lane = threadIdx.x & 63;
  int g = lane >> 4, l16 = lane & 15;
  int d = wave * 4 + g;                    // global dst row in [0,50000)
  bool dv = d < 50000;
  int dd = dv ? d : 49999;
  int dt = dd < 20000 ? 0 : (dd < 40000 ? 1 : 2);
  int dl = dd - TYPE_OFF[dt];
  float o[8] = {};
  int nr = NREL_OF[dt];
  for (int rr = 0; rr < nr; ++rr) {
    int r = RELS_OF[dt][rr];
    size_t wi = (size_t)layer * NREL + r;
    const u16* XL = XLb + (size_t)XOFF_S[r] * H;
    ushort8 uxr = *(const ushort8*)(XRb + (size_t)(XOFF_D[r] + dl) * H + l16 * 8);
    float4 a0 = *(const float4*)(att_a + wi * H + l16 * 8);
    float4 a1 = *(const float4*)(att_a + wi * H + l16 * 8 + 4);
    float av[8] = {a0.x, a0.y, a0.z, a0.w, a1.x, a1.y, a1.z, a1.w};
    float xr[8];
#pragma unroll
    for (int c = 0; c < 8; ++c) xr[c] = bf2f((u16)uxr[c]);
    const int* rpr = rp + SEG_RO[r + 1];
    const u32* pe = Ae + (size_t)r * EDG;
    int b = dv ? rpr[dl] : 0;
    int e = dv ? rpr[dl + 1] : 0;
    float m = -1e30f, s = 0.f;
    float V[8] = {};
    int j = b;
    if ((e - b) & 1) {                     // odd head: exact init (sc=0, w=1)
      int src = (int)(pe[j] & 32767u);
      ushort8 u0 = *(const ushort8*)(XL + (size_t)src * H + l16 * 8);
      float t = 0.f;
#pragma unroll
      for (int c = 0; c < 8; ++c) {
        V[c] = bf2f((u16)u0[c]);
        float v = V[c] + xr[c];
        t = fmaf(av[c], fmaxf(v, 0.2f * v), t);
      }
      t += __shfl_xor(t, 1, 64); t += __shfl_xor(t, 2, 64);
      t += __shfl_xor(t, 4, 64); t += __shfl_xor(t, 8, 64);
      s = 1.0f;
      m = t;
      ++j;
    }
    for (; j < e; j += 2) {                // two independent gathers in flight
      u32 p0 = pe[j], p1 = pe[j + 1];
      int s0 = (int)(p0 & 32767u), s1 = (int)(p1 & 32767u);
      ushort8 u0 = *(const ushort8*)(XL + (size_t)s0 * H + l16 * 8);
      ushort8 u1 = *(const ushort8*)(XL + (size_t)s1 * H + l16 * 8);
      float xl0[8], xl1[8], t0 = 0.f, t1 = 0.f;
#pragma unroll
      for (int c = 0; c < 8; ++c) {
        xl0[c] = bf2f((u16)u0[c]);
        xl1[c] = bf2f((u16)u1[c]);
        float v0 = xl0[c] + xr[c], v1 = xl1[c] + xr[c];
        t0 = fmaf(av[c], fmaxf(v0, 0.2f * v0), t0);
        t1 = fmaf(av[c], fmaxf(v1, 0.2f * v1), t1);
      }
      t0 += __shfl_xor(t0, 1, 64); t1 += __shfl_xor(t1, 1, 64);
      t0 += __shfl_xor(t0, 2, 64); t1 += __shfl_xor(t1, 2, 64);
      t0 += __shfl_xor(t0, 4, 64); t1 += __shfl_xor(t1, 4, 64);
      t0 += __shfl_xor(t0, 8, 64); t1 += __shfl_xor(t1, 8, 64);
      float nm = fmaxf(m, fmaxf(t0, t1));
      float sc = __expf(m - nm);
      float w0 = __expf(t0 - nm), w1 = __expf(t1 - nm);
      s = fmaf(s, sc, w0 + w1);
#pragma unroll
      for (int c = 0; c < 8; ++c)
        V[c] = fmaf(V[c], sc, fmaf(w0, xl0[c], w1 * xl1[c]));
      m = nm;
    }
    if (s > 0.f) {
      float inv = 1.0f / s;
#pragma unroll
      for (int c = 0; c < 8; ++c) o[c] = fmaf(V[c], inv, o[c]);
    }
    float4 c0 = *(const float4*)(cbv + wi * H + l16 * 8);
    float4 c1 = *(const float4*)(cbv + wi * H + l16 * 8 + 4);
    o[0] += c0.x; o[1] += c0.y; o[2] += c0.z; o[3] += c0.w;
    o[4] += c1.x; o[5] += c1.y; o[6] += c1.z; o[7] += c1.w;
  }
  if (dv) {
    float* ap = agg + (size_t)dd * H + l16 * 8;
    *(float4*)ap       = make_float4(o[0], o[1], o[2], o[3]);
    *(float4*)(ap + 4) = make_float4(o[4], o[5], o[6], o[7]);
  }
}

// ---------------- LayerNorm + ReLU (fp32 in, bf16 out) ----------------

__global__ __launch_bounds__(256) void ln_relu_kernel(const float* __restrict__ agg,
                                                      const float* __restrict__ g,
                                                      const float* __restrict__ b,
                                                      u16* __restrict__ xsb) {
  int row = (blockIdx.x * blockDim.x + threadIdx.x) >> 6;
  int lane = threadIdx.x & 63;
  if (row >= 50000) return;
  int t = row < 20000 ? 0 : (row < 40000 ? 1 : 2);
  float2 x = *(const float2*)(agg + (size_t)row * H + 2 * lane);
  float mu = wave_reduce_sum(x.x + x.y) * (1.f / 128.f);
  float d0 = x.x - mu, d1 = x.y - mu;
  float var = wave_reduce_sum(d0 * d0 + d1 * d1) * (1.f / 128.f);
  float inv = 1.0f / sqrtf(var + 1e-5f);
  float2 gg = *(const float2*)(g + t * H + 2 * lane);
  float2 bb = *(const float2*)(b + t * H + 2 * lane);
  float o0 = fmaxf(d0 * inv * gg.x + bb.x, 0.f);
  float o1 = fmaxf(d1 * inv * gg.y + bb.y, 0.f);
  u32 pk = (u32)f2bf(o0) | ((u32)f2bf(o1) << 16);
  *(u32*)(xsb + (size_t)row * H + 2 * lane) = pk;
}

// ---------------- prediction head ----------------

__global__ __launch_bounds__(256) void pred_kernel(const u16* __restrict__ xsb,
                                                   const float* __restrict__ Wp,
                                                   const float* __restrict__ bp,
                                                   float* __restrict__ out) {
  int row = (blockIdx.x * blockDim.x + threadIdx.x) >> 6;
  int lane = threadIdx.x & 63;
  if (row >= 20000) return;
  u32 u = *(const u32*)(xsb + (size_t)row * H + 2 * lane);
  float x0 = bflo(u), x1 = bfhi(u);
  float4 w = *(const float4*)(Wp + 4 * lane);
  float pA = x0 * w.x + x1 * w.z;
  float pB = x0 * w.y + x1 * w.w;
  pA = wave_reduce_sum(pA);
  pB = wave_reduce_sum(pB);
  if (lane == 0) {
    out[(size_t)row * 2 + 0] = pA + bp[0];
    out[(size_t)row * 2 + 1] = pB + bp[1];
  }
}

// ---------------- launch ----------------

extern "C" void kernel_launch(void* const* d_in, const int* in_sizes, int n_in,
                              void* d_out, int out_size, void* d_ws, size_t ws_size,
                              hipStream_t stream) {
  (void)in_sizes; (void)n_in; (void)out_size; (void)ws_size;
  const float* x_atom  = (const float*)d_in[0];
  const float* x_chem  = (const float*)d_in[1];
  const float* x_gene  = (const float*)d_in[2];
  const float* x_assay = (const float*)d_in[3];
  const float* W_mol   = (const float*)d_in[4];
  const float* Wl      = (const float*)d_in[5];
  const float* Wr      = (const float*)d_in[6];
  const float* bl      = (const float*)d_in[7];
  const float* br      = (const float*)d_in[8];
  const float* att_a   = (const float*)d_in[9];
  const float* cb      = (const float*)d_in[10];
  const float* ln_g    = (const float*)d_in[11];
  const float* ln_b    = (const float*)d_in[12];
  const float* Wp      = (const float*)d_in[13];
  const float* bp      = (const float*)d_in[14];
  const int*   hyper   = (const int*)d_in[15];
  const int*   ei      = (const int*)d_in[16];
  float* out = (float*)d_out;

  float* ws = (float*)d_ws;
  size_t o = 0;
  float* agg  = ws + o; o += (size_t)50000 * H;
  float* Mean = ws + o; o += (size_t)20000 * H;
  int2*  Aa   = (int2*)(ws + o); o += (size_t)2 * NATOM;
  int2*  Ba   = (int2*)(ws + o); o += (size_t)2 * NATOM;
  u32*   Ae   = (u32*)(ws + o); o += (size_t)NREL * EDG;
  u32*   Be   = (u32*)(ws + o); o += (size_t)NREL * EDG;
  int*   rp   = (int*)(ws + o); o += RP_TOTAL;
  int*   bh   = (int*)(ws + o); o += BH_TOTAL;
  u16*   xsb  = (u16*)(ws + o); o += (size_t)50000 * H / 2;
  u16*   WB   = (u16*)(ws + o); o += (size_t)52 * H * H / 2;
  u16*   XLb  = (u16*)(ws + o); o += (size_t)XTOT * H / 2;
  u16*   XRb  = (u16*)(ws + o); o += (size_t)XTOT * H / 2;

  dim3 b256(256);

  // ---- CSR build: atoms (int2) + edges (packed u32), 2-pass stable radix ----
  radix_init_a<<<dim3(2344), b256, 0, stream>>>(hyper, Aa);
  radix_init_e<<<dim3(1563, 13), b256, 0, stream>>>(ei, Ae);
  radix_count_t<int2><<<dim3(147, 1), b256, 0, stream>>>(Aa, bh, 0, 0);
  radix_count_t<u32><<<dim3(98, 13), b256, 0, stream>>>(Ae, bh, 15, 1);
  radix_scan<<<SEGS, b256, 0, stream>>>(bh);
  radix_scat_t<int2><<<dim3(147, 1), b256, 0, stream>>>(Aa, Ba, bh, 0, 0);
  radix_scat_t<u32><<<dim3(98, 13), b256, 0, stream>>>(Ae, Be, bh, 15, 1);
  radix_count_t<int2><<<dim3(147, 1), b256, 0, stream>>>(Ba, bh, 8, 0);
  radix_count_t<u32><<<dim3(98, 13), b256, 0, stream>>>(Be, bh, 23, 1);
  radix_scan<<<SEGS, b256, 0, stream>>>(bh);
  radix_scat_t<int2><<<dim3(147, 1), b256, 0, stream>>>(Ba, Aa, bh, 8, 0);
  radix_scat_t<u32><<<dim3(98, 13), b256, 0, stream>>>(Be, Ae, bh, 23, 1);
  build_rp_a<<<dim3(2344), b256, 0, stream>>>(Aa, rp);
  build_rp_e<<<dim3(1563, 13), b256, 0, stream>>>(Ae, rp);

  // ---- features: xsb[chem] = bf16(mean @ W_mol + x_chem); xsb[gene|assay] = bf16(raw) ----
  mean_atoms<<<dim3(20000 / 8), b256, 0, stream>>>(x_atom, rp, Aa, Mean);
  proj_kernel<<<dim3(313), b256, 0, stream>>>(Mean, W_mol, x_chem, xsb, 20000);
  conv_xs<<<dim3(3750), b256, 0, stream>>>(x_gene, x_assay, xsb);
  conv_weights<<<dim3(26, 2), b256, 0, stream>>>(Wl, Wr, WB);

  for (int l = 0; l < NLAYER; ++l) {
    proj_mfma<<<dim3(313, 26), b256, 0, stream>>>(xsb, WB, bl, br, XLb, XRb, l);
    gat_fused<<<dim3(3125), b256, 0, stream>>>(XLb, XRb, rp, Ae, att_a, cb, agg, l);
    ln_relu_kernel<<<dim3(50000 / 4), b256, 0, stream>>>(agg, ln_g + l * 3 * H, ln_b + l * 3 * H, xsb);
  }
  pred_kernel<<<dim3(20000 / 4), b256, 0, stream>>>(xsb, Wp, bp, out);
}